// Round 7
// baseline (679.502 us; speedup 1.0000x reference)
//
#include <hip/hip_runtime.h>
#include <hip/hip_bf16.h>
#include <math.h>

#define NPOS 16384   // B*H*W = 16*32*32
#define DD   512
#define PP   ((size_t)NPOS * DD)   // 8388608 elements per plane

typedef __bf16 bf16x8 __attribute__((ext_vector_type(8)));
typedef float  f32x4  __attribute__((ext_vector_type(4)));

// ---- async global->LDS, 16B per lane (global_load_lds_dwordx4) ----
__device__ __forceinline__ void gload16(const __bf16* g, __bf16* l) {
  __builtin_amdgcn_global_load_lds((__attribute__((address_space(1))) void*)(g),
                                   (__attribute__((address_space(3))) void*)(l), 16, 0, 0);
}
__device__ __forceinline__ void wait_vm0() { asm volatile("s_waitcnt vmcnt(0)" ::: "memory"); }
__device__ __forceinline__ void wait_vm2() { asm volatile("s_waitcnt vmcnt(2)" ::: "memory"); }
__device__ __forceinline__ void wait_vm3() { asm volatile("s_waitcnt vmcnt(3)" ::: "memory"); }
__device__ __forceinline__ void wait_lgkm0() { asm volatile("s_waitcnt lgkmcnt(0)" ::: "memory"); }

// ================= bf16 MFMA GEMM: A via LDS ring-3, B DIRECT from L2 =================
// R6 diagnosis: R4->R5 gain ratio (43.6->~33us) tracks LDS-bytes-per-MFMA (1.25->1.0KB),
// not occupancy -> GEMMs are ~60%-efficient LDS-pipe-bound. Lever: cut LDS bytes/MFMA.
// B panels are 0.5-1MB bf16 = L2-resident (tr_k wrote them; 4MB L2/XCD). So B skips LDS:
//   * B-frags read direct from global as bf16x8 (16 rows x 64B/row, all L2 hits),
//     PREFETCHED one K-tile ahead into regs (T14) -> off the barrier critical path.
//   * A keeps the proven gload_lds 16B ring-3 (1 load/tile: 512 lanes x 16B = 8KB tile).
//   * LDS per tile: 64KB -> 40KB (A write 8 + A frag reads 4KB x 8 waves).
//   * tile-end wait vmcnt(3): A(t+2) + 2x B(t+1) stay in flight (never drains);
//     forces A(t+1) + B(t) landed regardless of compiler's intra-iter load order
//     (asm "memory" clobber pins the window). ONE barrier per tile (ring-3 reuse).
//   * LDS block 40KB: ring 24KB; epi1 full-line shuffle epilogue uses all 40KB.
// 8 waves (2M x 4N, 64x32/wave, acc[4][2] in AGPRs), launch_bounds(512,4) -> 2 blocks/CU.
// Grid: 1-D, bijective XCD swizzle; ntc fastest -> A-sharers same XCD (A L2-reuse).
// epi 0: C0 fp32 (ld N) = acc + bias
// epi 1: N=1024; bn<512 -> C1b bf16 (ld 512); bn>=512 -> sigmoid -> C1 bf16 (ld 512)
// epi 2: C0 fp32 (ld N) = acc + bias + res
__global__ __launch_bounds__(512, 4) void gemm_k(
    const __bf16* __restrict__ A, const __bf16* __restrict__ Bt,
    const float* __restrict__ bias, const float* __restrict__ res,
    float* __restrict__ C0, __bf16* __restrict__ C1, __bf16* __restrict__ C1b,
    int N, int K, int epi)
{
  __shared__ __bf16 SM[20480];          // 40 KB; A ring = first 24 KB
  __bf16 (*Asm)[4096] = (__bf16(*)[4096])SM;

  const int tid  = threadIdx.x;
  const int w    = tid >> 6;
  const int lane = tid & 63;
  const int quad = lane >> 4;
  const int l16  = lane & 15;
  const int wm   = (w >> 2) << 6;       // 2 M-waves x 64 rows
  const int wn   = (w & 3) << 5;        // 4 N-waves x 32 cols

  // grid decode: bijective XCD swizzle, then ntc fastest (A-sharers adjacent per XCD)
  const int nwg = gridDim.x;
  const int cpx = nwg >> 3;
  const int lin = (blockIdx.x & 7) * cpx + (blockIdx.x >> 3);
  const int nbn = N >> 7;               // 128-wide N tiles (4 or 8)
  const int sh  = (nbn == 8) ? 3 : 2;
  const int mt  = lin >> sh;
  const int ntc = lin & (nbn - 1);
  const int bm  = mt << 7;
  const int bn  = ntc << 7;

  const __bf16* Ab = A + (size_t)bm * K;
  // B direct row pointers for this wave's two 16-col frag groups (quad picks k-subchunk)
  const __bf16* Bp0 = Bt + (size_t)(bn + wn + l16) * K + quad * 8;
  const __bf16* Bp1 = Bp0 + (size_t)16 * K;
  const int nk = K >> 5;

  f32x4 acc[4][2];
  #pragma unroll
  for (int i = 0; i < 4; ++i)
    #pragma unroll
    for (int j = 0; j < 2; ++j) acc[i][j] = (f32x4){0.f, 0.f, 0.f, 0.f};

  // A staging: 512 threads x 16B = whole 128x32 tile. LDS lane-linear (gload_lds
  // requirement); global col-chunk pre-swizzled so swizzled frag reads see linear
  // data (rule 21): LDS[r][sl] = G[r][sl ^ ((r>>1)&3)].
  #define STG_A(tile, buf) {                                                     \
    const int r_ = tid >> 2, c_ = tid & 3;                                       \
    gload16(Ab + (size_t)r_ * K + ((tile) << 5) + ((c_ ^ ((r_ >> 1) & 3)) << 3), \
            &Asm[buf][tid << 3]);                                                \
  }

  // prologue: A tiles 0,1 staged; B(0) loaded; one full drain (once)
  STG_A(0, 0)
  STG_A(1, 1)
  bf16x8 b0 = *(const bf16x8*)(Bp0);
  bf16x8 b1 = *(const bf16x8*)(Bp1);
  wait_vm0();
  __builtin_amdgcn_s_barrier();

  int cur = 0;
  for (int t = 0; t < nk; ++t) {
    const int nx2 = (cur == 0) ? 2 : cur - 1;    // (cur+2)%3 : buffer for tile t+2

    // issue A(t+2) DMA + B(t+1) reg-prefetch (both ride across the barrier)
    if (t + 2 < nk) STG_A(t + 2, nx2)
    bf16x8 bn0 = b0, bn1 = b1;
    if (t + 1 < nk) {
      bn0 = *(const bf16x8*)(Bp0 + ((t + 1) << 5));
      bn1 = *(const bf16x8*)(Bp1 + ((t + 1) << 5));
    }

    // A frag reads from buf[cur] (landed: forced by last iter's vmcnt wait + barrier)
    bf16x8 af[4];
    #pragma unroll
    for (int i = 0; i < 4; ++i) {
      const int m = wm + i * 16 + l16;
      af[i] = *(const bf16x8*)(&Asm[cur][m * 32 + ((quad ^ ((m >> 1) & 3)) << 3)]);
    }

    __builtin_amdgcn_s_setprio(1);
    #pragma unroll
    for (int i = 0; i < 4; ++i) {
      acc[i][0] = __builtin_amdgcn_mfma_f32_16x16x32_bf16(af[i], b0, acc[i][0], 0, 0, 0);
      acc[i][1] = __builtin_amdgcn_mfma_f32_16x16x32_bf16(af[i], b1, acc[i][1], 0, 0, 0);
    }
    __builtin_amdgcn_s_setprio(0);

    // tile end: counted wait leaves {A(t+2), B(t+1)x2} in flight; forces A(t+1)
    // landed (whatever the intra-window issue order). Never drains mid-loop.
    if (t + 2 < nk)      { wait_vm3(); }
    else if (t + 1 < nk) { wait_vm2(); }
    __builtin_amdgcn_s_barrier();
    b0 = bn0; b1 = bn1;
    cur = (cur == 2) ? 0 : cur + 1;
  }
  #undef STG_A

  // ---- epilogue. C/D layout: col = lane&15, row = quad*4 + reg  [m89-verified] ----
  if (epi == 1) {
    // full-line bf16 path: scatter through per-wave LDS (64 rows x 80B stride), read
    // back bf16x8 -> 16B/lane stores; each 4-lane group covers a full 64B line.
    const bool dosig = (bn >= 512);
    __bf16* dst = dosig ? C1 : C1b;
    const int cb = dosig ? (bn - 512) : bn;
    char* wb = (char*)SM + w * 5120;             // 8 waves x 5120 B = 40 KB exact
    #pragma unroll
    for (int i = 0; i < 4; ++i)
      #pragma unroll
      for (int j = 0; j < 2; ++j) {
        const float bv = bias[bn + wn + j * 16 + l16];
        #pragma unroll
        for (int r = 0; r < 4; ++r) {
          float v = acc[i][j][r] + bv;
          if (dosig) v = 1.f / (1.f + expf(-v));
          *(__bf16*)(wb + (i * 16 + quad * 4 + r) * 80 + (j * 16 + l16) * 2) = (__bf16)v;
        }
      }
    wait_lgkm0();                                 // wave-local; no barrier needed
    #pragma unroll
    for (int s = 0; s < 4; ++s) {
      const int rr = s * 16 + (lane >> 2);        // 0..63 within wave tile
      bf16x8 vv = *(bf16x8*)(wb + rr * 80 + (lane & 3) * 16);
      const int grow = bm + wm + rr;
      *(bf16x8*)(dst + (size_t)grow * 512 + cb + wn + (lane & 3) * 8) = vv;
    }
  } else {
    // fp32 path: 16 lanes x 4B = full 64B line per store group already
    #pragma unroll
    for (int j = 0; j < 2; ++j) {
      const int col = wn + j * 16 + l16;
      const float bv = bias[bn + col];
      #pragma unroll
      for (int i = 0; i < 4; ++i) {
        const int row0 = bm + wm + i * 16 + quad * 4;
        #pragma unroll
        for (int r = 0; r < 4; ++r) {
          float v = acc[i][j][r] + bv;
          size_t off = (size_t)(row0 + r) * N + bn + col;
          if (epi == 2) v += res[off];
          C0[off] = v;
        }
      }
    }
  }
}

// ---------------- fp32 -> bf16 elementwise (tokens) ----------------
__global__ __launch_bounds__(256) void cvt_k(const float* __restrict__ s, __bf16* __restrict__ d)
{
  size_t i = ((size_t)blockIdx.x * 256 + threadIdx.x) * 8;
  float4 a = *(const float4*)(s + i);
  float4 b = *(const float4*)(s + i + 4);
  bf16x8 v;
  v[0] = (__bf16)a.x; v[1] = (__bf16)a.y; v[2] = (__bf16)a.z; v[3] = (__bf16)a.w;
  v[4] = (__bf16)b.x; v[5] = (__bf16)b.y; v[6] = (__bf16)b.z; v[7] = (__bf16)b.w;
  *(bf16x8*)(d + i) = v;
}

// ---------------- transpose KxN fp32 -> NxK bf16 (weights) ----------------
__global__ __launch_bounds__(256) void tr_k(const float* __restrict__ src, __bf16* __restrict__ dst,
                                            int K, int N, size_t sstr, size_t dstr)
{
  __shared__ float t[32][33];
  const float* s = src + blockIdx.z * sstr;
  __bf16* d = dst + blockIdx.z * dstr;
  int n0 = blockIdx.x * 32, k0 = blockIdx.y * 32;
  int tx = threadIdx.x & 31, ty = threadIdx.x >> 5;   // 32x8
  #pragma unroll
  for (int i = 0; i < 4; ++i)
    t[ty + i * 8][tx] = s[(size_t)(k0 + ty + i * 8) * N + n0 + tx];
  __syncthreads();
  #pragma unroll
  for (int i = 0; i < 4; ++i)
    d[(size_t)(n0 + ty + i * 8) * K + k0 + tx] = (__bf16)t[tx][ty + i * 8];
}

// ---------------- LayerNorm over D=512, one wave per position, bf16 out ----------------
__global__ __launch_bounds__(256) void ln_k(const float* __restrict__ x, const float* __restrict__ w,
                                            const float* __restrict__ bv, __bf16* __restrict__ out)
{
  int gw = (blockIdx.x * 256 + threadIdx.x) >> 6;   // position
  int lane = threadIdx.x & 63;
  const float* xp = x + ((size_t)gw << 9) + lane * 8;
  float4 u0 = *(const float4*)xp;
  float4 u1 = *(const float4*)(xp + 4);
  float v[8] = {u0.x,u0.y,u0.z,u0.w,u1.x,u1.y,u1.z,u1.w};
  float s = 0.f;
  #pragma unroll
  for (int j = 0; j < 8; ++j) s += v[j];
  #pragma unroll
  for (int off = 32; off; off >>= 1) s += __shfl_xor(s, off, 64);
  float mu = s * (1.f/512.f);
  float q = 0.f;
  #pragma unroll
  for (int j = 0; j < 8; ++j) { float d = v[j] - mu; q += d*d; }
  #pragma unroll
  for (int off = 32; off; off >>= 1) q += __shfl_xor(q, off, 64);
  float rstd = rsqrtf(q * (1.f/512.f) + 1e-5f);
  int dch = lane * 8;
  float4 w0 = *(const float4*)(w + dch),  w1 = *(const float4*)(w + dch + 4);
  float4 b0 = *(const float4*)(bv + dch), b1 = *(const float4*)(bv + dch + 4);
  float wv[8] = {w0.x,w0.y,w0.z,w0.w,w1.x,w1.y,w1.z,w1.w};
  float bb[8] = {b0.x,b0.y,b0.z,b0.w,b1.x,b1.y,b1.z,b1.w};
  bf16x8 ov;
  #pragma unroll
  for (int j = 0; j < 8; ++j) ov[j] = (__bf16)((v[j] - mu) * rstd * wv[j] + bb[j]);
  *(bf16x8*)(out + ((size_t)gw << 9) + dch) = ov;
}

// ================= Fully-fused conv + 2D scan, 16 ch/block, 2 blocks/CU (R4-proven) =================
__device__ __forceinline__ float sig_a(float al) {
  float a = 1.f / (1.f + expf(-al));
  return fminf(fmaxf(a, 1e-4f), 1.f - 1e-4f);
}

#define CST 544   // chunk stride in elements: 32*16 + 32 pad (1088 B)

__global__ __launch_bounds__(512, 4) void scan2d_k(
    const __bf16* __restrict__ xin, const float* __restrict__ cw, const float* __restrict__ cb,
    const float* __restrict__ alog, const float* __restrict__ bvec, const float* __restrict__ cvec,
    const float* __restrict__ dvec, const __bf16* __restrict__ gate, __bf16* __restrict__ yo)
{
  __shared__ __bf16 T[32 * CST];    // xin tile; partial park in phase C. 34 KB
  __shared__ __bf16 Y[32 * CST];    // u tile. 34 KB
  __shared__ float  S[4][32][16];   // chunk sums: rowF,rowB,colF,colB. 8 KB
  const int tid = threadIdx.x;
  const int bx  = blockIdx.x;
  const int cg  = ((bx & 7) << 2) | (bx >> 3);   // channel group of 16; line-mates same XCD
  const int b   = blockIdx.y;
  const int ch  = tid & 15;
  const int c0  = tid >> 4;         // 0..31; thread owns chunk c0
  const int d   = (cg << 4) + ch;

  const float a   = sig_a(alog[d]);
  const float lna = logf(a);
  const float ia  = 1.f / a;
  const float bb  = bvec[d];
  const float sc  = 0.25f * cvec[d];
  const float dd  = dvec[d];

  const __bf16* ub = xin + ((size_t)b << 19) + (cg << 4);

  // ---- load xin tile: 4 x bf16x8 per thread, 16 B/lane ----
  #pragma unroll
  for (int i = 0; i < 4; ++i) {
    int f = tid + i * 512;          // 16B chunk id, 0..2047
    int pos = f >> 1, half = f & 1;
    *(bf16x8*)(T + (pos >> 5) * CST + ((pos & 31) << 4) + (half << 3))
        = *(const bf16x8*)(ub + (size_t)pos * 512 + (half << 3));
  }
  // conv weights while loads are in flight
  float w00 = cw[(0 << 9) + d], w01 = cw[(1 << 9) + d], w02 = cw[(2 << 9) + d];
  float w10 = cw[(3 << 9) + d], w11 = cw[(4 << 9) + d], w12 = cw[(5 << 9) + d];
  float w20 = cw[(6 << 9) + d], w21 = cw[(7 << 9) + d], w22 = cw[(8 << 9) + d];
  const float cbv = cb[d];
  // scan bases (loop-invariant; direct expf avoids 0*inf at extreme a)
  const float A0f = expf((float)(c0 << 5) * lna),        R0f = expf((float)(c0 << 5) * -lna);
  const float A0b = expf((float)((31 - c0) << 5) * lna), R0b = expf((float)((31 - c0) << 5) * -lna);
  __syncthreads();

  // ---- phase 0: depthwise 3x3 conv + SiLU, row c0 -> Y ----
  {
    const bool up = (c0 > 0);
    const bool dn = (c0 < 31);
    float a0 = 0.f, a1 = 0.f, a2 = 0.f;                                  // col -1
    float b0 = up ? (float)T[(c0 - 1) * CST + ch] : 0.f;                 // col 0
    float b1 =      (float)T[c0 * CST + ch];
    float b2 = dn ? (float)T[(c0 + 1) * CST + ch] : 0.f;
    #pragma unroll 4
    for (int ww = 0; ww < 32; ++ww) {
      float e0 = 0.f, e1 = 0.f, e2 = 0.f;                                // col ww+1
      if (ww < 31) {
        e0 = up ? (float)T[(c0 - 1) * CST + ((ww + 1) << 4) + ch] : 0.f;
        e1 =      (float)T[c0 * CST + ((ww + 1) << 4) + ch];
        e2 = dn ? (float)T[(c0 + 1) * CST + ((ww + 1) << 4) + ch] : 0.f;
      }
      float acc0 = cbv;
      acc0 = fmaf(a0, w00, acc0); acc0 = fmaf(b0, w01, acc0); acc0 = fmaf(e0, w02, acc0);
      acc0 = fmaf(a1, w10, acc0); acc0 = fmaf(b1, w11, acc0); acc0 = fmaf(e1, w12, acc0);
      acc0 = fmaf(a2, w20, acc0); acc0 = fmaf(b2, w21, acc0); acc0 = fmaf(e2, w22, acc0);
      acc0 = acc0 / (1.f + expf(-acc0));
      Y[c0 * CST + (ww << 4) + ch] = (__bf16)acc0;
      a0 = b0; a1 = b1; a2 = b2; b0 = e0; b1 = e1; b2 = e2;
    }
  }
  __syncthreads();

  // one scan step: r += u*bb/max(apr,1e-20) with tracked reciprocal
  #define STEP(r_, uu_, apr_, rp_)                                 \
    { float rr_ = (apr_ < 1e-20f) ? 1e20f : rp_;                   \
      r_ = fmaf((uu_) * bb, rr_, r_); }

  // ---- phase A: 4 chunk sums (rowF/rowB/colF/colB) in one loop ----
  {
    float pf = A0f, qf = R0f, pb = A0b, qb = R0b;
    float s0 = 0.f, s1 = 0.f, s2 = 0.f, s3 = 0.f;
    #pragma unroll 4
    for (int j = 0; j < 32; ++j) {
      float urf = (float)Y[c0 * CST + (j << 4) + ch];
      float urb = (float)Y[c0 * CST + ((31 - j) << 4) + ch];
      float ucf = (float)Y[j * CST + (c0 << 4) + ch];
      float ucb = (float)Y[(31 - j) * CST + (c0 << 4) + ch];
      STEP(s0, urf, pf, qf)  STEP(s2, ucf, pf, qf)
      STEP(s1, urb, pb, qb)  STEP(s3, ucb, pb, qb)
      pf *= a; qf *= ia; pb *= a; qb *= ia;
    }
    S[0][c0][ch] = s0; S[1][c0][ch] = s1; S[2][c0][ch] = s2; S[3][c0][ch] = s3;
  }
  __syncthreads();

  // ---- phase B: exclusive prefix (F arrays) / exclusive suffix (B arrays) ----
  if (tid < 64) {
    int arr = tid >> 4, ch2 = tid & 15;
    float run = 0.f;
    if ((arr & 1) == 0) {
      #pragma unroll 4
      for (int cc = 0; cc < 32; ++cc) { float v = S[arr][cc][ch2]; S[arr][cc][ch2] = run; run += v; }
    } else {
      #pragma unroll 4
      for (int cc = 31; cc >= 0; --cc) { float v = S[arr][cc][ch2]; S[arr][cc][ch2] = run; run += v; }
    }
  }
  __syncthreads();

  // ---- C-col fwd: raw partial -> T  (column c0: pos = j*32+c0 -> chunk j, in-chunk c0) ----
  {
    float r = S[2][c0][ch];
    float p = A0f, q = R0f;
    #pragma unroll 4
    for (int j = 0; j < 32; ++j) {
      int i0 = j * CST + (c0 << 4) + ch;
      float u = (float)Y[i0];
      float ap = fmaxf(p, 1e-20f);
      STEP(r, u, p, q)
      T[i0] = (__bf16)(r * ap);
      p *= a; q *= ia;
    }
  }
  // ---- C-col bwd: T = sc*(T + r*ap)  [same-thread RMW] ----
  {
    float r = S[3][c0][ch];
    float p = A0b, q = R0b;
    #pragma unroll 4
    for (int j = 31; j >= 0; --j) {
      int i0 = j * CST + (c0 << 4) + ch;
      float u = (float)Y[i0];
      float ap = fmaxf(p, 1e-20f);
      STEP(r, u, p, q)
      T[i0] = (__bf16)(sc * ((float)T[i0] + r * ap));
      p *= a; q *= ia;
    }
  }
  __syncthreads();   // row threads read other threads' col finals

  // ---- C-row fwd: T += sc*(r*ap)  (row c0: chunk c0, in-chunk j) ----
  {
    float r = S[0][c0][ch];
    float p = A0f, q = R0f;
    #pragma unroll 4
    for (int j = 0; j < 32; ++j) {
      int i0 = c0 * CST + (j << 4) + ch;
      float u = (float)Y[i0];
      float ap = fmaxf(p, 1e-20f);
      STEP(r, u, p, q)
      T[i0] = (__bf16)((float)T[i0] + sc * (r * ap));
      p *= a; q *= ia;
    }
  }
  // ---- C-row bwd: finalize + d*u, *gate, write out ----
  {
    const __bf16* gb = gate + ((size_t)b << 19) + (cg << 4) + ch;
    __bf16* yb = yo + ((size_t)b << 19) + (cg << 4) + ch;
    float r = S[1][c0][ch];
    float p = A0b, q = R0b;
    #pragma unroll 4
    for (int j = 31; j >= 0; --j) {
      int pp = (c0 << 5) + j;
      int i0 = c0 * CST + (j << 4) + ch;
      float u = (float)Y[i0];
      float ap = fmaxf(p, 1e-20f);
      STEP(r, u, p, q)
      float y0 = (float)T[i0] + sc * (r * ap) + dd * u;
      yb[(size_t)pp * 512] = (__bf16)(y0 * (float)gb[(size_t)pp * 512]);
      p *= a; q *= ia;
    }
  }
  #undef STEP
}

// ---------------- mean over 1024 positions (bf16 in) -> (16, 512) fp32 ----------------
__global__ __launch_bounds__(256) void reduce_k(const __bf16* __restrict__ hn, float* __restrict__ out)
{
  __shared__ float part[4][64];
  int l = threadIdx.x & 63;       // channel within group
  int q = threadIdx.x >> 6;       // position quarter
  int d = blockIdx.y * 64 + l;
  int b = blockIdx.x;
  const __bf16* p = hn + ((size_t)b << 19) + d + ((size_t)(q * 256) << 9);
  float s0 = 0.f, s1 = 0.f, s2 = 0.f, s3 = 0.f;
  for (int t = 0; t < 256; t += 4) {
    s0 += (float)p[(size_t)(t+0) << 9];
    s1 += (float)p[(size_t)(t+1) << 9];
    s2 += (float)p[(size_t)(t+2) << 9];
    s3 += (float)p[(size_t)(t+3) << 9];
  }
  part[q][l] = (s0 + s1) + (s2 + s3);
  __syncthreads();
  if (threadIdx.x < 64)
    out[b * 512 + d] = (part[0][l] + part[1][l] + part[2][l] + part[3][l]) * (1.f / 1024.f);
}

extern "C" void kernel_launch(void* const* d_in, const int* in_sizes, int n_in,
                              void* d_out, int out_size, void* d_ws, size_t ws_size,
                              hipStream_t stream)
{
  const float* tokens = (const float*)d_in[0];
  const float* in_w   = (const float*)d_in[1];
  const float* in_b   = (const float*)d_in[2];
  const float* nw     = (const float*)d_in[3];
  const float* nb     = (const float*)d_in[4];
  const float* iw     = (const float*)d_in[5];
  const float* ib     = (const float*)d_in[6];
  const float* cw     = (const float*)d_in[7];
  const float* cb     = (const float*)d_in[8];
  const float* al     = (const float*)d_in[9];
  const float* bbv    = (const float*)d_in[10];
  const float* ccv    = (const float*)d_in[11];
  const float* ddv    = (const float*)d_in[12];
  const float* ow     = (const float*)d_in[13];
  const float* obv    = (const float*)d_in[14];
  const float* onw    = (const float*)d_in[15];
  const float* onb    = (const float*)d_in[16];

  // workspace layout (~115 MB):
  float*  x     = (float*)d_ws;                      // fp32 residual (33.5 MB)
  __bf16* hy16  = (__bf16*)(x + PP);                 // bf16 h / yg / final-ln (16.8 MB)
  __bf16* xin16 = hy16 + PP;                         // bf16 x_in (16.8 MB)
  __bf16* g16   = xin16 + PP;                        // bf16 gate (16.8 MB)
  __bf16* iwT   = g16 + PP;                          // 4x(1024x512) bf16 (4.2 MB)
  __bf16* owT   = iwT + (size_t)4 * 1024 * 512;      // 4x(512x512) bf16 (2.1 MB)
  __bf16* tb16  = owT + (size_t)4 * 512 * 512;       // tokens bf16 (25.2 MB)
  __bf16* inwT  = xin16;                             // in_proj_w^T bf16 (pre-loop alias)

  // --- weight/input conversion (once per launch) ---
  cvt_k<<<6144, 256, 0, stream>>>(tokens, tb16);
  tr_k<<<dim3(16, 24, 1), 256, 0, stream>>>(in_w, inwT, 768, 512, 0, 0);
  tr_k<<<dim3(32, 16, 4), 256, 0, stream>>>(iw, iwT, 512, 1024, (size_t)512*1024, (size_t)1024*512);
  tr_k<<<dim3(16, 16, 4), 256, 0, stream>>>(ow, owT, 512, 512, (size_t)512*512, (size_t)512*512);

  // x = tokens @ in_proj_w + b   (128 M-tiles x 4 N-tiles = 512 blocks, 2/CU)
  gemm_k<<<512, 512, 0, stream>>>(tb16, inwT, in_b, nullptr, x, nullptr, nullptr,
                                  512, 768, 0);

  for (int i = 0; i < 4; ++i) {
    ln_k<<<4096, 256, 0, stream>>>(x, nw + i*512, nb + i*512, hy16);
    // (h @ iw + ib): 128 x 8 = 1024 blocks
    gemm_k<<<1024, 512, 0, stream>>>(hy16, iwT + (size_t)i*1024*512, ib + i*1024,
                                     nullptr, nullptr, g16, xin16, 1024, 512, 1);
    // 32 ch-groups x 16 batch = 512 blocks, 2/CU
    scan2d_k<<<dim3(32, 16), 512, 0, stream>>>(xin16, cw + i*9*512, cb + i*512,
                                               al + i*512, bbv + i*512, ccv + i*512,
                                               ddv + i*512, g16, hy16);
    // (yg @ ow + ob + x): 128 x 4 = 512 blocks
    gemm_k<<<512, 512, 0, stream>>>(hy16, owT + (size_t)i*512*512, obv + i*512,
                                    x, x, nullptr, nullptr, 512, 512, 2);
  }

  ln_k<<<4096, 256, 0, stream>>>(x, onw, onb, hy16);
  reduce_k<<<dim3(16, 8), 256, 0, stream>>>(hy16, (float*)d_out);
}

// Round 8
// 598.721 us; speedup vs baseline: 1.1349x; 1.1349x over previous
//
#include <hip/hip_runtime.h>
#include <hip/hip_bf16.h>
#include <math.h>

#define NPOS 16384   // B*H*W = 16*32*32
#define DD   512
#define PP   ((size_t)NPOS * DD)   // 8388608 elements per plane

typedef __bf16 bf16x8 __attribute__((ext_vector_type(8)));
typedef float  f32x4  __attribute__((ext_vector_type(4)));

// ---- async global->LDS, 16B per lane (global_load_lds_dwordx4) ----
__device__ __forceinline__ void gload16(const __bf16* g, __bf16* l) {
  __builtin_amdgcn_global_load_lds((__attribute__((address_space(1))) void*)(g),
                                   (__attribute__((address_space(3))) void*)(l), 16, 0, 0);
}
__device__ __forceinline__ void wait_vm0() { asm volatile("s_waitcnt vmcnt(0)" ::: "memory"); }
__device__ __forceinline__ void wait_vm2() { asm volatile("s_waitcnt vmcnt(2)" ::: "memory"); }
__device__ __forceinline__ void wait_vm3() { asm volatile("s_waitcnt vmcnt(3)" ::: "memory"); }
__device__ __forceinline__ void wait_lgkm0() { asm volatile("s_waitcnt lgkmcnt(0)" ::: "memory"); }

// ================= bf16 MFMA GEMM, 128x128 / 8 waves, two K-loop flavors =================
// R8 post-mortem of R7: B-direct-from-L2 with 1-tile prefetch REGRESSED epi0/epi2
// (35->63us; only 2 blocks/CU on their 512-block grids -> B L2 latency exposed on the
// MFMA critical path every iteration). epi1 (1024-block grid, 40KB -> 4 blocks/CU) was
// NOT in the regressed top-5. Split:
//   * BDIR=0 (epi0/epi2, 512-block grids): R5-proven loop — A+B both via gload_lds
//     ring-3 (48KB), counted s_waitcnt vmcnt(2) at tile end. Measured-good (535us total).
//   * BDIR=1 (epi1, 1024-block grid): A via gload_lds ring-3 (24KB) + B direct from L2
//     with 2-TILE prefetch depth (rotate 3 reg pairs: use B(t), hold B(t+1), load
//     B(t+2)). Tile-end vmcnt(3) forces {A(t+1),B(t+1)} landed, leaves {A(t+2),
//     B(t+2)x2} in flight — never drains. LDS 40KB -> 4 blocks/CU (160KB exact).
// Both: global-side XOR swizzle for conflict-free A/B frag ds_read_b128 (rule 21);
// 8 waves 2Mx4N (64x32/wave, acc[4][2]); s_setprio around MFMA; one barrier/tile;
// bijective XCD swizzle, ntc fastest (A-sharers same XCD).
// epi 0: C0 fp32 (ld N) = acc + bias
// epi 1: N=1024; bn<512 -> C1b bf16 (ld 512); bn>=512 -> sigmoid -> C1 bf16 (ld 512)
//        (full-line bf16 epilogue via per-wave LDS shuffle, 64 rows x 80B)
// epi 2: C0 fp32 (ld N) = acc + bias + res
template<int BDIR>
__global__ __launch_bounds__(512, 4) void gemm_k(
    const __bf16* __restrict__ A, const __bf16* __restrict__ Bt,
    const float* __restrict__ bias, const float* __restrict__ res,
    float* __restrict__ C0, __bf16* __restrict__ C1, __bf16* __restrict__ C1b,
    int N, int K, int epi)
{
  __shared__ __bf16 SM[BDIR ? 20480 : 24576];   // 40 KB / 48 KB
  __bf16 (*Asm)[4096] = (__bf16(*)[4096])SM;
  __bf16 (*Bsm)[4096] = (__bf16(*)[4096])(SM + 3 * 4096);  // BDIR=0 only

  const int tid  = threadIdx.x;
  const int w    = tid >> 6;
  const int lane = tid & 63;
  const int quad = lane >> 4;
  const int l16  = lane & 15;
  const int wm   = (w >> 2) << 6;       // 2 M-waves x 64 rows
  const int wn   = (w & 3) << 5;        // 4 N-waves x 32 cols

  // grid decode: bijective XCD swizzle, then ntc fastest (A-sharers adjacent per XCD)
  const int nwg = gridDim.x;
  const int cpx = nwg >> 3;
  const int lin = (blockIdx.x & 7) * cpx + (blockIdx.x >> 3);
  const int nbn = N >> 7;               // 128-wide N tiles (4 or 8)
  const int sh  = (nbn == 8) ? 3 : 2;
  const int mt  = lin >> sh;
  const int ntc = lin & (nbn - 1);
  const int bm  = mt << 7;
  const int bn  = ntc << 7;

  const __bf16* Ab = A + (size_t)bm * K;
  const __bf16* Bb = Bt + (size_t)bn * K;
  // BDIR=1: per-wave B row pointers (16 rows x 64B per frag group; quad = k-subchunk)
  const __bf16* Bp0 = Bt + (size_t)(bn + wn + l16) * K + quad * 8;
  const __bf16* Bp1 = Bp0 + (size_t)16 * K;
  const int nk = K >> 5;

  f32x4 acc[4][2];
  #pragma unroll
  for (int i = 0; i < 4; ++i)
    #pragma unroll
    for (int j = 0; j < 2; ++j) acc[i][j] = (f32x4){0.f, 0.f, 0.f, 0.f};

  // staging: 512 threads x 16B = whole 128x32 tile. LDS lane-linear (gload_lds
  // requirement); global col-chunk pre-swizzled so swizzled frag reads see linear
  // data (rule 21): LDS[r][sl] = G[r][sl ^ ((r>>1)&3)].
  #define STG(P, gb, tile, buf) {                                               \
    const int r_ = tid >> 2, c_ = tid & 3;                                      \
    gload16(gb + (size_t)r_ * K + ((tile) << 5) + ((c_ ^ ((r_ >> 1) & 3)) << 3),\
            &P[buf][tid << 3]);                                                 \
  }

  int cur = 0;
  if constexpr (BDIR == 0) {
    // ---------- R5-proven loop: A+B LDS ring-3, counted vmcnt(2) ----------
    STG(Asm, Ab, 0, 0) STG(Bsm, Bb, 0, 0)
    STG(Asm, Ab, 1, 1) STG(Bsm, Bb, 1, 1)
    wait_vm2();
    __builtin_amdgcn_s_barrier();

    for (int t = 0; t < nk; ++t) {
      const int nx2 = (cur == 0) ? 2 : cur - 1;
      const bool st = (t + 2 < nk);
      if (st) {
        STG(Asm, Ab, t + 2, nx2)
        STG(Bsm, Bb, t + 2, nx2)
      }
      bf16x8 af[4], bfr[2];
      #pragma unroll
      for (int i = 0; i < 4; ++i) {
        const int m = wm + i * 16 + l16;
        af[i] = *(const bf16x8*)(&Asm[cur][m * 32 + ((quad ^ ((m >> 1) & 3)) << 3)]);
      }
      #pragma unroll
      for (int j = 0; j < 2; ++j) {
        const int n = wn + j * 16 + l16;
        bfr[j] = *(const bf16x8*)(&Bsm[cur][n * 32 + ((quad ^ ((n >> 1) & 3)) << 3)]);
      }
      __builtin_amdgcn_s_setprio(1);
      #pragma unroll
      for (int i = 0; i < 4; ++i) {
        acc[i][0] = __builtin_amdgcn_mfma_f32_16x16x32_bf16(af[i], bfr[0], acc[i][0], 0, 0, 0);
        acc[i][1] = __builtin_amdgcn_mfma_f32_16x16x32_bf16(af[i], bfr[1], acc[i][1], 0, 0, 0);
      }
      __builtin_amdgcn_s_setprio(0);
      if (st) { wait_vm2(); } else { wait_vm0(); }
      __builtin_amdgcn_s_barrier();
      cur = (cur == 2) ? 0 : cur + 1;
    }
  } else {
    // ---------- A ring-3 + B direct depth-2 (R7 fix: 1->2 tile B distance) ----------
    STG(Asm, Ab, 0, 0)
    STG(Asm, Ab, 1, 1)
    bf16x8 bq0 = *(const bf16x8*)(Bp0);               // B(0)
    bf16x8 bq1 = *(const bf16x8*)(Bp1);
    bf16x8 br0 = *(const bf16x8*)(Bp0 + 32);          // B(1)
    bf16x8 br1 = *(const bf16x8*)(Bp1 + 32);
    wait_vm0();
    __builtin_amdgcn_s_barrier();

    for (int t = 0; t < nk; ++t) {
      const int nx2 = (cur == 0) ? 2 : cur - 1;
      const bool st = (t + 2 < nk);
      bf16x8 bs0 = br0, bs1 = br1;
      if (st) {
        STG(Asm, Ab, t + 2, nx2)
        bs0 = *(const bf16x8*)(Bp0 + ((t + 2) << 5)); // B(t+2), 2-tile depth
        bs1 = *(const bf16x8*)(Bp1 + ((t + 2) << 5));
      }
      bf16x8 af[4];
      #pragma unroll
      for (int i = 0; i < 4; ++i) {
        const int m = wm + i * 16 + l16;
        af[i] = *(const bf16x8*)(&Asm[cur][m * 32 + ((quad ^ ((m >> 1) & 3)) << 3)]);
      }
      __builtin_amdgcn_s_setprio(1);
      #pragma unroll
      for (int i = 0; i < 4; ++i) {
        acc[i][0] = __builtin_amdgcn_mfma_f32_16x16x32_bf16(af[i], bq0, acc[i][0], 0, 0, 0);
        acc[i][1] = __builtin_amdgcn_mfma_f32_16x16x32_bf16(af[i], bq1, acc[i][1], 0, 0, 0);
      }
      __builtin_amdgcn_s_setprio(0);
      // end: {A(t+2), B(t+2)x2} stay in flight; forces {A(t+1), B(t+1)x2} landed.
      if (st) { wait_vm3(); } else if (t + 1 < nk) { wait_vm0(); }
      __builtin_amdgcn_s_barrier();
      bq0 = br0; bq1 = br1; br0 = bs0; br1 = bs1;
      cur = (cur == 2) ? 0 : cur + 1;
    }
  }
  #undef STG

  // ---- epilogue. C/D layout: col = lane&15, row = quad*4 + reg  [m89-verified] ----
  if (epi == 1) {
    // full-line bf16 path: scatter through per-wave LDS (64 rows x 80B stride), read
    // back bf16x8 -> 16B/lane stores; each 4-lane group covers a full 64B line.
    const bool dosig = (bn >= 512);
    __bf16* dst = dosig ? C1 : C1b;
    const int cb = dosig ? (bn - 512) : bn;
    char* wb = (char*)SM + w * 5120;             // 8 waves x 5120 B = 40 KB
    #pragma unroll
    for (int i = 0; i < 4; ++i)
      #pragma unroll
      for (int j = 0; j < 2; ++j) {
        const float bv = bias[bn + wn + j * 16 + l16];
        #pragma unroll
        for (int r = 0; r < 4; ++r) {
          float v = acc[i][j][r] + bv;
          if (dosig) v = 1.f / (1.f + expf(-v));
          *(__bf16*)(wb + (i * 16 + quad * 4 + r) * 80 + (j * 16 + l16) * 2) = (__bf16)v;
        }
      }
    wait_lgkm0();                                 // wave-local; no barrier needed
    #pragma unroll
    for (int s = 0; s < 4; ++s) {
      const int rr = s * 16 + (lane >> 2);        // 0..63 within wave tile
      bf16x8 vv = *(bf16x8*)(wb + rr * 80 + (lane & 3) * 16);
      const int grow = bm + wm + rr;
      *(bf16x8*)(dst + (size_t)grow * 512 + cb + wn + (lane & 3) * 8) = vv;
    }
  } else {
    // fp32 path: 16 lanes x 4B = full 64B line per store group already
    #pragma unroll
    for (int j = 0; j < 2; ++j) {
      const int col = wn + j * 16 + l16;
      const float bv = bias[bn + col];
      #pragma unroll
      for (int i = 0; i < 4; ++i) {
        const int row0 = bm + wm + i * 16 + quad * 4;
        #pragma unroll
        for (int r = 0; r < 4; ++r) {
          float v = acc[i][j][r] + bv;
          size_t off = (size_t)(row0 + r) * N + bn + col;
          if (epi == 2) v += res[off];
          C0[off] = v;
        }
      }
    }
  }
}

// ---------------- fp32 -> bf16 elementwise (tokens) ----------------
__global__ __launch_bounds__(256) void cvt_k(const float* __restrict__ s, __bf16* __restrict__ d)
{
  size_t i = ((size_t)blockIdx.x * 256 + threadIdx.x) * 8;
  float4 a = *(const float4*)(s + i);
  float4 b = *(const float4*)(s + i + 4);
  bf16x8 v;
  v[0] = (__bf16)a.x; v[1] = (__bf16)a.y; v[2] = (__bf16)a.z; v[3] = (__bf16)a.w;
  v[4] = (__bf16)b.x; v[5] = (__bf16)b.y; v[6] = (__bf16)b.z; v[7] = (__bf16)b.w;
  *(bf16x8*)(d + i) = v;
}

// ---------------- transpose KxN fp32 -> NxK bf16 (weights) ----------------
__global__ __launch_bounds__(256) void tr_k(const float* __restrict__ src, __bf16* __restrict__ dst,
                                            int K, int N, size_t sstr, size_t dstr)
{
  __shared__ float t[32][33];
  const float* s = src + blockIdx.z * sstr;
  __bf16* d = dst + blockIdx.z * dstr;
  int n0 = blockIdx.x * 32, k0 = blockIdx.y * 32;
  int tx = threadIdx.x & 31, ty = threadIdx.x >> 5;   // 32x8
  #pragma unroll
  for (int i = 0; i < 4; ++i)
    t[ty + i * 8][tx] = s[(size_t)(k0 + ty + i * 8) * N + n0 + tx];
  __syncthreads();
  #pragma unroll
  for (int i = 0; i < 4; ++i)
    d[(size_t)(n0 + ty + i * 8) * K + k0 + tx] = (__bf16)t[tx][ty + i * 8];
}

// ---------------- LayerNorm over D=512, one wave per position, bf16 out ----------------
__global__ __launch_bounds__(256) void ln_k(const float* __restrict__ x, const float* __restrict__ w,
                                            const float* __restrict__ bv, __bf16* __restrict__ out)
{
  int gw = (blockIdx.x * 256 + threadIdx.x) >> 6;   // position
  int lane = threadIdx.x & 63;
  const float* xp = x + ((size_t)gw << 9) + lane * 8;
  float4 u0 = *(const float4*)xp;
  float4 u1 = *(const float4*)(xp + 4);
  float v[8] = {u0.x,u0.y,u0.z,u0.w,u1.x,u1.y,u1.z,u1.w};
  float s = 0.f;
  #pragma unroll
  for (int j = 0; j < 8; ++j) s += v[j];
  #pragma unroll
  for (int off = 32; off; off >>= 1) s += __shfl_xor(s, off, 64);
  float mu = s * (1.f/512.f);
  float q = 0.f;
  #pragma unroll
  for (int j = 0; j < 8; ++j) { float d = v[j] - mu; q += d*d; }
  #pragma unroll
  for (int off = 32; off; off >>= 1) q += __shfl_xor(q, off, 64);
  float rstd = rsqrtf(q * (1.f/512.f) + 1e-5f);
  int dch = lane * 8;
  float4 w0 = *(const float4*)(w + dch),  w1 = *(const float4*)(w + dch + 4);
  float4 b0 = *(const float4*)(bv + dch), b1 = *(const float4*)(bv + dch + 4);
  float wv[8] = {w0.x,w0.y,w0.z,w0.w,w1.x,w1.y,w1.z,w1.w};
  float bb[8] = {b0.x,b0.y,b0.z,b0.w,b1.x,b1.y,b1.z,b1.w};
  bf16x8 ov;
  #pragma unroll
  for (int j = 0; j < 8; ++j) ov[j] = (__bf16)((v[j] - mu) * rstd * wv[j] + bb[j]);
  *(bf16x8*)(out + ((size_t)gw << 9) + dch) = ov;
}

// ================= Fully-fused conv + 2D scan, 16 ch/block, 2 blocks/CU (R4-proven) =================
__device__ __forceinline__ float sig_a(float al) {
  float a = 1.f / (1.f + expf(-al));
  return fminf(fmaxf(a, 1e-4f), 1.f - 1e-4f);
}

#define CST 544   // chunk stride in elements: 32*16 + 32 pad (1088 B)

__global__ __launch_bounds__(512, 4) void scan2d_k(
    const __bf16* __restrict__ xin, const float* __restrict__ cw, const float* __restrict__ cb,
    const float* __restrict__ alog, const float* __restrict__ bvec, const float* __restrict__ cvec,
    const float* __restrict__ dvec, const __bf16* __restrict__ gate, __bf16* __restrict__ yo)
{
  __shared__ __bf16 T[32 * CST];    // xin tile; partial park in phase C. 34 KB
  __shared__ __bf16 Y[32 * CST];    // u tile. 34 KB
  __shared__ float  S[4][32][16];   // chunk sums: rowF,rowB,colF,colB. 8 KB
  const int tid = threadIdx.x;
  const int bx  = blockIdx.x;
  const int cg  = ((bx & 7) << 2) | (bx >> 3);   // channel group of 16; line-mates same XCD
  const int b   = blockIdx.y;
  const int ch  = tid & 15;
  const int c0  = tid >> 4;         // 0..31; thread owns chunk c0
  const int d   = (cg << 4) + ch;

  const float a   = sig_a(alog[d]);
  const float lna = logf(a);
  const float ia  = 1.f / a;
  const float bb  = bvec[d];
  const float sc  = 0.25f * cvec[d];
  const float dd  = dvec[d];

  const __bf16* ub = xin + ((size_t)b << 19) + (cg << 4);

  // ---- load xin tile: 4 x bf16x8 per thread, 16 B/lane ----
  #pragma unroll
  for (int i = 0; i < 4; ++i) {
    int f = tid + i * 512;          // 16B chunk id, 0..2047
    int pos = f >> 1, half = f & 1;
    *(bf16x8*)(T + (pos >> 5) * CST + ((pos & 31) << 4) + (half << 3))
        = *(const bf16x8*)(ub + (size_t)pos * 512 + (half << 3));
  }
  // conv weights while loads are in flight
  float w00 = cw[(0 << 9) + d], w01 = cw[(1 << 9) + d], w02 = cw[(2 << 9) + d];
  float w10 = cw[(3 << 9) + d], w11 = cw[(4 << 9) + d], w12 = cw[(5 << 9) + d];
  float w20 = cw[(6 << 9) + d], w21 = cw[(7 << 9) + d], w22 = cw[(8 << 9) + d];
  const float cbv = cb[d];
  // scan bases (loop-invariant; direct expf avoids 0*inf at extreme a)
  const float A0f = expf((float)(c0 << 5) * lna),        R0f = expf((float)(c0 << 5) * -lna);
  const float A0b = expf((float)((31 - c0) << 5) * lna), R0b = expf((float)((31 - c0) << 5) * -lna);
  __syncthreads();

  // ---- phase 0: depthwise 3x3 conv + SiLU, row c0 -> Y ----
  {
    const bool up = (c0 > 0);
    const bool dn = (c0 < 31);
    float a0 = 0.f, a1 = 0.f, a2 = 0.f;                                  // col -1
    float b0 = up ? (float)T[(c0 - 1) * CST + ch] : 0.f;                 // col 0
    float b1 =      (float)T[c0 * CST + ch];
    float b2 = dn ? (float)T[(c0 + 1) * CST + ch] : 0.f;
    #pragma unroll 4
    for (int ww = 0; ww < 32; ++ww) {
      float e0 = 0.f, e1 = 0.f, e2 = 0.f;                                // col ww+1
      if (ww < 31) {
        e0 = up ? (float)T[(c0 - 1) * CST + ((ww + 1) << 4) + ch] : 0.f;
        e1 =      (float)T[c0 * CST + ((ww + 1) << 4) + ch];
        e2 = dn ? (float)T[(c0 + 1) * CST + ((ww + 1) << 4) + ch] : 0.f;
      }
      float acc0 = cbv;
      acc0 = fmaf(a0, w00, acc0); acc0 = fmaf(b0, w01, acc0); acc0 = fmaf(e0, w02, acc0);
      acc0 = fmaf(a1, w10, acc0); acc0 = fmaf(b1, w11, acc0); acc0 = fmaf(e1, w12, acc0);
      acc0 = fmaf(a2, w20, acc0); acc0 = fmaf(b2, w21, acc0); acc0 = fmaf(e2, w22, acc0);
      acc0 = acc0 / (1.f + expf(-acc0));
      Y[c0 * CST + (ww << 4) + ch] = (__bf16)acc0;
      a0 = b0; a1 = b1; a2 = b2; b0 = e0; b1 = e1; b2 = e2;
    }
  }
  __syncthreads();

  // one scan step: r += u*bb/max(apr,1e-20) with tracked reciprocal
  #define STEP(r_, uu_, apr_, rp_)                                 \
    { float rr_ = (apr_ < 1e-20f) ? 1e20f : rp_;                   \
      r_ = fmaf((uu_) * bb, rr_, r_); }

  // ---- phase A: 4 chunk sums (rowF/rowB/colF/colB) in one loop ----
  {
    float pf = A0f, qf = R0f, pb = A0b, qb = R0b;
    float s0 = 0.f, s1 = 0.f, s2 = 0.f, s3 = 0.f;
    #pragma unroll 4
    for (int j = 0; j < 32; ++j) {
      float urf = (float)Y[c0 * CST + (j << 4) + ch];
      float urb = (float)Y[c0 * CST + ((31 - j) << 4) + ch];
      float ucf = (float)Y[j * CST + (c0 << 4) + ch];
      float ucb = (float)Y[(31 - j) * CST + (c0 << 4) + ch];
      STEP(s0, urf, pf, qf)  STEP(s2, ucf, pf, qf)
      STEP(s1, urb, pb, qb)  STEP(s3, ucb, pb, qb)
      pf *= a; qf *= ia; pb *= a; qb *= ia;
    }
    S[0][c0][ch] = s0; S[1][c0][ch] = s1; S[2][c0][ch] = s2; S[3][c0][ch] = s3;
  }
  __syncthreads();

  // ---- phase B: exclusive prefix (F arrays) / exclusive suffix (B arrays) ----
  if (tid < 64) {
    int arr = tid >> 4, ch2 = tid & 15;
    float run = 0.f;
    if ((arr & 1) == 0) {
      #pragma unroll 4
      for (int cc = 0; cc < 32; ++cc) { float v = S[arr][cc][ch2]; S[arr][cc][ch2] = run; run += v; }
    } else {
      #pragma unroll 4
      for (int cc = 31; cc >= 0; --cc) { float v = S[arr][cc][ch2]; S[arr][cc][ch2] = run; run += v; }
    }
  }
  __syncthreads();

  // ---- C-col fwd: raw partial -> T  (column c0: pos = j*32+c0 -> chunk j, in-chunk c0) ----
  {
    float r = S[2][c0][ch];
    float p = A0f, q = R0f;
    #pragma unroll 4
    for (int j = 0; j < 32; ++j) {
      int i0 = j * CST + (c0 << 4) + ch;
      float u = (float)Y[i0];
      float ap = fmaxf(p, 1e-20f);
      STEP(r, u, p, q)
      T[i0] = (__bf16)(r * ap);
      p *= a; q *= ia;
    }
  }
  // ---- C-col bwd: T = sc*(T + r*ap)  [same-thread RMW] ----
  {
    float r = S[3][c0][ch];
    float p = A0b, q = R0b;
    #pragma unroll 4
    for (int j = 31; j >= 0; --j) {
      int i0 = j * CST + (c0 << 4) + ch;
      float u = (float)Y[i0];
      float ap = fmaxf(p, 1e-20f);
      STEP(r, u, p, q)
      T[i0] = (__bf16)(sc * ((float)T[i0] + r * ap));
      p *= a; q *= ia;
    }
  }
  __syncthreads();   // row threads read other threads' col finals

  // ---- C-row fwd: T += sc*(r*ap)  (row c0: chunk c0, in-chunk j) ----
  {
    float r = S[0][c0][ch];
    float p = A0f, q = R0f;
    #pragma unroll 4
    for (int j = 0; j < 32; ++j) {
      int i0 = c0 * CST + (j << 4) + ch;
      float u = (float)Y[i0];
      float ap = fmaxf(p, 1e-20f);
      STEP(r, u, p, q)
      T[i0] = (__bf16)((float)T[i0] + sc * (r * ap));
      p *= a; q *= ia;
    }
  }
  // ---- C-row bwd: finalize + d*u, *gate, write out ----
  {
    const __bf16* gb = gate + ((size_t)b << 19) + (cg << 4) + ch;
    __bf16* yb = yo + ((size_t)b << 19) + (cg << 4) + ch;
    float r = S[1][c0][ch];
    float p = A0b, q = R0b;
    #pragma unroll 4
    for (int j = 31; j >= 0; --j) {
      int pp = (c0 << 5) + j;
      int i0 = c0 * CST + (j << 4) + ch;
      float u = (float)Y[i0];
      float ap = fmaxf(p, 1e-20f);
      STEP(r, u, p, q)
      float y0 = (float)T[i0] + sc * (r * ap) + dd * u;
      yb[(size_t)pp * 512] = (__bf16)(y0 * (float)gb[(size_t)pp * 512]);
      p *= a; q *= ia;
    }
  }
  #undef STEP
}

// ---------------- mean over 1024 positions (bf16 in) -> (16, 512) fp32 ----------------
__global__ __launch_bounds__(256) void reduce_k(const __bf16* __restrict__ hn, float* __restrict__ out)
{
  __shared__ float part[4][64];
  int l = threadIdx.x & 63;       // channel within group
  int q = threadIdx.x >> 6;       // position quarter
  int d = blockIdx.y * 64 + l;
  int b = blockIdx.x;
  const __bf16* p = hn + ((size_t)b << 19) + d + ((size_t)(q * 256) << 9);
  float s0 = 0.f, s1 = 0.f, s2 = 0.f, s3 = 0.f;
  for (int t = 0; t < 256; t += 4) {
    s0 += (float)p[(size_t)(t+0) << 9];
    s1 += (float)p[(size_t)(t+1) << 9];
    s2 += (float)p[(size_t)(t+2) << 9];
    s3 += (float)p[(size_t)(t+3) << 9];
  }
  part[q][l] = (s0 + s1) + (s2 + s3);
  __syncthreads();
  if (threadIdx.x < 64)
    out[b * 512 + d] = (part[0][l] + part[1][l] + part[2][l] + part[3][l]) * (1.f / 1024.f);
}

extern "C" void kernel_launch(void* const* d_in, const int* in_sizes, int n_in,
                              void* d_out, int out_size, void* d_ws, size_t ws_size,
                              hipStream_t stream)
{
  const float* tokens = (const float*)d_in[0];
  const float* in_w   = (const float*)d_in[1];
  const float* in_b   = (const float*)d_in[2];
  const float* nw     = (const float*)d_in[3];
  const float* nb     = (const float*)d_in[4];
  const float* iw     = (const float*)d_in[5];
  const float* ib     = (const float*)d_in[6];
  const float* cw     = (const float*)d_in[7];
  const float* cb     = (const float*)d_in[8];
  const float* al     = (const float*)d_in[9];
  const float* bbv    = (const float*)d_in[10];
  const float* ccv    = (const float*)d_in[11];
  const float* ddv    = (const float*)d_in[12];
  const float* ow     = (const float*)d_in[13];
  const float* obv    = (const float*)d_in[14];
  const float* onw    = (const float*)d_in[15];
  const float* onb    = (const float*)d_in[16];

  // workspace layout (~115 MB):
  float*  x     = (float*)d_ws;                      // fp32 residual (33.5 MB)
  __bf16* hy16  = (__bf16*)(x + PP);                 // bf16 h / yg / final-ln (16.8 MB)
  __bf16* xin16 = hy16 + PP;                         // bf16 x_in (16.8 MB)
  __bf16* g16   = xin16 + PP;                        // bf16 gate (16.8 MB)
  __bf16* iwT   = g16 + PP;                          // 4x(1024x512) bf16 (4.2 MB)
  __bf16* owT   = iwT + (size_t)4 * 1024 * 512;      // 4x(512x512) bf16 (2.1 MB)
  __bf16* tb16  = owT + (size_t)4 * 512 * 512;       // tokens bf16 (25.2 MB)
  __bf16* inwT  = xin16;                             // in_proj_w^T bf16 (pre-loop alias)

  // --- weight/input conversion (once per launch) ---
  cvt_k<<<6144, 256, 0, stream>>>(tokens, tb16);
  tr_k<<<dim3(16, 24, 1), 256, 0, stream>>>(in_w, inwT, 768, 512, 0, 0);
  tr_k<<<dim3(32, 16, 4), 256, 0, stream>>>(iw, iwT, 512, 1024, (size_t)512*1024, (size_t)1024*512);
  tr_k<<<dim3(16, 16, 4), 256, 0, stream>>>(ow, owT, 512, 512, (size_t)512*512, (size_t)512*512);

  // x = tokens @ in_proj_w + b   (128 M-tiles x 4 N-tiles = 512 blocks, 2/CU)
  gemm_k<0><<<512, 512, 0, stream>>>(tb16, inwT, in_b, nullptr, x, nullptr, nullptr,
                                     512, 768, 0);

  for (int i = 0; i < 4; ++i) {
    ln_k<<<4096, 256, 0, stream>>>(x, nw + i*512, nb + i*512, hy16);
    // (h @ iw + ib): 128 x 8 = 1024 blocks, 40KB -> 4 blocks/CU
    gemm_k<1><<<1024, 512, 0, stream>>>(hy16, iwT + (size_t)i*1024*512, ib + i*1024,
                                        nullptr, nullptr, g16, xin16, 1024, 512, 1);
    // 32 ch-groups x 16 batch = 512 blocks, 2/CU
    scan2d_k<<<dim3(32, 16), 512, 0, stream>>>(xin16, cw + i*9*512, cb + i*512,
                                               al + i*512, bbv + i*512, ccv + i*512,
                                               ddv + i*512, g16, hy16);
    // (yg @ ow + ob + x): 128 x 4 = 512 blocks (R5-proven path)
    gemm_k<0><<<512, 512, 0, stream>>>(hy16, owT + (size_t)i*512*512, obv + i*512,
                                       x, x, nullptr, nullptr, 512, 512, 2);
  }

  ln_k<<<4096, 256, 0, stream>>>(x, onw, onb, hy16);
  reduce_k<<<dim3(16, 8), 256, 0, stream>>>(hy16, (float*)d_out);
}

// Round 9
// 566.273 us; speedup vs baseline: 1.2000x; 1.0573x over previous
//
#include <hip/hip_runtime.h>
#include <hip/hip_bf16.h>
#include <math.h>

#define NPOS 16384   // B*H*W = 16*32*32
#define DD   512
#define PP   ((size_t)NPOS * DD)   // 8388608 elements per plane

typedef __bf16 bf16x8 __attribute__((ext_vector_type(8)));
typedef float  f32x4  __attribute__((ext_vector_type(4)));

// ---- async global->LDS, 16B per lane (global_load_lds_dwordx4) ----
__device__ __forceinline__ void gload16(const __bf16* g, __bf16* l) {
  __builtin_amdgcn_global_load_lds((__attribute__((address_space(1))) void*)(g),
                                   (__attribute__((address_space(3))) void*)(l), 16, 0, 0);
}
__device__ __forceinline__ void wait_vm0() { asm volatile("s_waitcnt vmcnt(0)" ::: "memory"); }
__device__ __forceinline__ void wait_vm2() { asm volatile("s_waitcnt vmcnt(2)" ::: "memory"); }
__device__ __forceinline__ void wait_vm3() { asm volatile("s_waitcnt vmcnt(3)" ::: "memory"); }
__device__ __forceinline__ void wait_lgkm0() { asm volatile("s_waitcnt lgkmcnt(0)" ::: "memory"); }

// ================= bf16 MFMA GEMM, all-LDS ring-3, two tile shapes =================
// R9: R7/R8 proved B-direct-from-L2 always loses (depth-1 AND depth-2) -> B stays in
// LDS. Remaining epi1 inefficiencies vs R5 (all-LDS 128^2, 1024 blocks, 3/CU):
//   (a) grid tail: 1024 blocks at 3/CU = 768 resident + 256 ragged second round;
//   (b) LDS bytes/MFMA = 1.0 KB (stage 16KB + frag 48KB per 64-MFMA K-tile).
// BN256=1 (epi1): 128x256 tile, 8 waves 2Mx4N (wave 64x64, acc[4][4]).
//   grid 128x4 = 512 blocks @ 72KB ring-3 -> exactly 2/CU, fully resident, NO tail;
//   per K-tile: stage 24KB + frag 64KB / 128 MFMA = 0.69 KB/MFMA (-31%).
//   Staging 3 loads/tile (A x1, B x2); counted vmcnt(3) at tile end (t+1 landed,
//   t+2's 3 in flight - never drains). Epilogue: R3-verbatim 64x64 per-wave LDS
//   shuffle (144B stride, 8x9216B = 72KB exact) -> bf16x8 full-line stores.
// BN256=0 (epi0/epi2): byte-exact R5 loop - 128^2, A+B ring-3 48KB, vmcnt(2),
//   fp32 direct full-line epilogue. Measured-good (535.8us total).
// Both: global-side XOR swizzle (c ^ ((row>>1)&3)) -> conflict-free frag ds_read_b128
// (rule 21); s_setprio around MFMA; ONE barrier per K-tile; bijective XCD swizzle with
// ntc fastest (A-sharers same XCD).
// epi 0: C0 fp32 (ld N) = acc + bias
// epi 1: N=1024; bn<512 -> C1b bf16 (ld 512); bn>=512 -> sigmoid -> C1 bf16 (ld 512)
// epi 2: C0 fp32 (ld N) = acc + bias + res
template<int BN256>
__global__ __launch_bounds__(512, 4) void gemm_k(
    const __bf16* __restrict__ A, const __bf16* __restrict__ Bt,
    const float* __restrict__ bias, const float* __restrict__ res,
    float* __restrict__ C0, __bf16* __restrict__ C1, __bf16* __restrict__ C1b,
    int N, int K, int epi)
{
  __shared__ __bf16 SM[BN256 ? 36864 : 24576];            // 72 KB / 48 KB
  __bf16 (*Asm)[4096]  = (__bf16(*)[4096])SM;             // 3 x 8 KB
  __bf16 (*Bsm)[4096]  = (__bf16(*)[4096])(SM + 12288);   // BN256=0: 3 x 8 KB
  __bf16 (*BsmW)[8192] = (__bf16(*)[8192])(SM + 12288);   // BN256=1: 3 x 16 KB

  const int tid  = threadIdx.x;
  const int w    = tid >> 6;
  const int lane = tid & 63;
  const int quad = lane >> 4;
  const int l16  = lane & 15;
  const int wm   = (w >> 2) << 6;                   // 2 M-waves x 64 rows
  const int wn   = (w & 3) << (BN256 ? 6 : 5);      // 4 N-waves x 64/32 cols
  constexpr int JW = BN256 ? 4 : 2;                 // 16-col frag groups per wave

  // grid decode: bijective XCD swizzle, then ntc fastest (A-sharers adjacent per XCD)
  const int nwg = gridDim.x;
  const int cpx = nwg >> 3;
  const int lin = (blockIdx.x & 7) * cpx + (blockIdx.x >> 3);
  const int nbn = BN256 ? (N >> 8) : (N >> 7);
  const int sh  = (nbn == 8) ? 3 : ((nbn == 4) ? 2 : 1);
  const int mt  = lin >> sh;
  const int ntc = lin & (nbn - 1);
  const int bm  = mt << 7;
  const int bn  = ntc << (BN256 ? 8 : 7);

  const __bf16* Ab = A  + (size_t)bm * K;
  const __bf16* Bb = Bt + (size_t)bn * K;
  const int nk = K >> 5;

  f32x4 acc[4][JW];
  #pragma unroll
  for (int i = 0; i < 4; ++i)
    #pragma unroll
    for (int j = 0; j < JW; ++j) acc[i][j] = (f32x4){0.f, 0.f, 0.f, 0.f};

  // staging: LDS lane-linear (gload_lds requirement); global col-chunk pre-swizzled so
  // swizzled frag reads see linear data (rule 21): LDS[r][sl] = G[r][sl ^ ((r>>1)&3)].
  #define STG_A(tile, buf) {                                                     \
    const int r_ = tid >> 2, c_ = tid & 3;                                       \
    gload16(Ab + (size_t)r_ * K + ((tile) << 5) + ((c_ ^ ((r_ >> 1) & 3)) << 3), \
            &Asm[buf][tid << 3]);                                                \
  }
  #define STG_B(tile, buf) {                                                     \
    const int r_ = tid >> 2, c_ = tid & 3;                                       \
    gload16(Bb + (size_t)r_ * K + ((tile) << 5) + ((c_ ^ ((r_ >> 1) & 3)) << 3), \
            &Bsm[buf][tid << 3]);                                                \
  }
  #define STG_B2(tile, buf, k2) {                                                \
    const int ch_ = tid + ((k2) << 9);                                           \
    const int r_ = ch_ >> 2, c_ = ch_ & 3;                                       \
    gload16(Bb + (size_t)r_ * K + ((tile) << 5) + ((c_ ^ ((r_ >> 1) & 3)) << 3), \
            &BsmW[buf][ch_ << 3]);                                               \
  }

  int cur = 0;
  if constexpr (BN256 == 0) {
    // ---------- R5-proven loop: A+B LDS ring-3, counted vmcnt(2) ----------
    STG_A(0, 0) STG_B(0, 0)
    STG_A(1, 1) STG_B(1, 1)
    wait_vm2();
    __builtin_amdgcn_s_barrier();

    for (int t = 0; t < nk; ++t) {
      const int nx2 = (cur == 0) ? 2 : cur - 1;
      const bool st = (t + 2 < nk);
      if (st) {
        STG_A(t + 2, nx2)
        STG_B(t + 2, nx2)
      }
      bf16x8 af[4], bfr[2];
      #pragma unroll
      for (int i = 0; i < 4; ++i) {
        const int m = wm + i * 16 + l16;
        af[i] = *(const bf16x8*)(&Asm[cur][m * 32 + ((quad ^ ((m >> 1) & 3)) << 3)]);
      }
      #pragma unroll
      for (int j = 0; j < 2; ++j) {
        const int n = wn + j * 16 + l16;
        bfr[j] = *(const bf16x8*)(&Bsm[cur][n * 32 + ((quad ^ ((n >> 1) & 3)) << 3)]);
      }
      __builtin_amdgcn_s_setprio(1);
      #pragma unroll
      for (int i = 0; i < 4; ++i) {
        acc[i][0] = __builtin_amdgcn_mfma_f32_16x16x32_bf16(af[i], bfr[0], acc[i][0], 0, 0, 0);
        acc[i][1] = __builtin_amdgcn_mfma_f32_16x16x32_bf16(af[i], bfr[1], acc[i][1], 0, 0, 0);
      }
      __builtin_amdgcn_s_setprio(0);
      if (st) { wait_vm2(); } else { wait_vm0(); }
      __builtin_amdgcn_s_barrier();
      cur = (cur == 2) ? 0 : cur + 1;
    }
  } else {
    // ---------- 128x256: A ring-3 + wide-B ring-3, counted vmcnt(3) ----------
    STG_A(0, 0) STG_B2(0, 0, 0) STG_B2(0, 0, 1)
    STG_A(1, 1) STG_B2(1, 1, 0) STG_B2(1, 1, 1)
    wait_vm3();
    __builtin_amdgcn_s_barrier();

    for (int t = 0; t < nk; ++t) {
      const int nx2 = (cur == 0) ? 2 : cur - 1;
      const bool st = (t + 2 < nk);
      if (st) {
        STG_A(t + 2, nx2)
        STG_B2(t + 2, nx2, 0)
        STG_B2(t + 2, nx2, 1)
      }
      bf16x8 af[4], bfr[4];
      #pragma unroll
      for (int i = 0; i < 4; ++i) {
        const int m = wm + i * 16 + l16;
        af[i] = *(const bf16x8*)(&Asm[cur][m * 32 + ((quad ^ ((m >> 1) & 3)) << 3)]);
      }
      #pragma unroll
      for (int j = 0; j < 4; ++j) {
        const int n = wn + j * 16 + l16;
        bfr[j] = *(const bf16x8*)(&BsmW[cur][n * 32 + ((quad ^ ((n >> 1) & 3)) << 3)]);
      }
      __builtin_amdgcn_s_setprio(1);
      #pragma unroll
      for (int i = 0; i < 4; ++i)
        #pragma unroll
        for (int j = 0; j < 4; ++j)
          acc[i][j] = __builtin_amdgcn_mfma_f32_16x16x32_bf16(af[i], bfr[j], acc[i][j], 0, 0, 0);
      __builtin_amdgcn_s_setprio(0);
      if (st) { wait_vm3(); } else { wait_vm0(); }
      __builtin_amdgcn_s_barrier();
      cur = (cur == 2) ? 0 : cur + 1;
    }
  }
  #undef STG_A
  #undef STG_B
  #undef STG_B2

  // ---- epilogue. C/D layout: col = lane&15, row = quad*4 + reg  [m89-verified] ----
  if constexpr (BN256) {
    // epi1 only: full-line bf16 via per-wave LDS shuffle (64 rows x 144B stride;
    // 8 waves x 9216 B = 72 KB exact), bf16x8 stores -> full 64B lines.
    const bool dosig = (bn >= 512);
    __bf16* dst = dosig ? C1 : C1b;
    const int cb = dosig ? (bn - 512) : bn;
    char* wb = (char*)SM + w * 9216;
    #pragma unroll
    for (int i = 0; i < 4; ++i)
      #pragma unroll
      for (int j = 0; j < 4; ++j) {
        const float bv = bias[bn + wn + j * 16 + l16];
        #pragma unroll
        for (int r = 0; r < 4; ++r) {
          float v = acc[i][j][r] + bv;
          if (dosig) v = 1.f / (1.f + expf(-v));
          *(__bf16*)(wb + (i * 16 + quad * 4 + r) * 144 + (j * 16 + l16) * 2) = (__bf16)v;
        }
      }
    wait_lgkm0();                                 // wave-local; no barrier needed
    #pragma unroll
    for (int i = 0; i < 4; ++i)
      #pragma unroll
      for (int h = 0; h < 2; ++h) {
        const int rr = (lane >> 3) + h * 8;       // 0..15 within i-block
        bf16x8 vv = *(bf16x8*)(wb + (i * 16 + rr) * 144 + (lane & 7) * 16);
        const int grow = bm + wm + i * 16 + rr;
        *(bf16x8*)(dst + (size_t)grow * 512 + cb + wn + (lane & 7) * 8) = vv;
      }
  } else {
    // fp32 path: 16 lanes x 4B = full 64B line per store group already
    #pragma unroll
    for (int j = 0; j < 2; ++j) {
      const int col = wn + j * 16 + l16;
      const float bv = bias[bn + col];
      #pragma unroll
      for (int i = 0; i < 4; ++i) {
        const int row0 = bm + wm + i * 16 + quad * 4;
        #pragma unroll
        for (int r = 0; r < 4; ++r) {
          float v = acc[i][j][r] + bv;
          size_t off = (size_t)(row0 + r) * N + bn + col;
          if (epi == 2) v += res[off];
          C0[off] = v;
        }
      }
    }
  }
}

// ---------------- fp32 -> bf16 elementwise (tokens) ----------------
__global__ __launch_bounds__(256) void cvt_k(const float* __restrict__ s, __bf16* __restrict__ d)
{
  size_t i = ((size_t)blockIdx.x * 256 + threadIdx.x) * 8;
  float4 a = *(const float4*)(s + i);
  float4 b = *(const float4*)(s + i + 4);
  bf16x8 v;
  v[0] = (__bf16)a.x; v[1] = (__bf16)a.y; v[2] = (__bf16)a.z; v[3] = (__bf16)a.w;
  v[4] = (__bf16)b.x; v[5] = (__bf16)b.y; v[6] = (__bf16)b.z; v[7] = (__bf16)b.w;
  *(bf16x8*)(d + i) = v;
}

// ---------------- transpose KxN fp32 -> NxK bf16 (weights) ----------------
__global__ __launch_bounds__(256) void tr_k(const float* __restrict__ src, __bf16* __restrict__ dst,
                                            int K, int N, size_t sstr, size_t dstr)
{
  __shared__ float t[32][33];
  const float* s = src + blockIdx.z * sstr;
  __bf16* d = dst + blockIdx.z * dstr;
  int n0 = blockIdx.x * 32, k0 = blockIdx.y * 32;
  int tx = threadIdx.x & 31, ty = threadIdx.x >> 5;   // 32x8
  #pragma unroll
  for (int i = 0; i < 4; ++i)
    t[ty + i * 8][tx] = s[(size_t)(k0 + ty + i * 8) * N + n0 + tx];
  __syncthreads();
  #pragma unroll
  for (int i = 0; i < 4; ++i)
    d[(size_t)(n0 + ty + i * 8) * K + k0 + tx] = (__bf16)t[tx][ty + i * 8];
}

// ---------------- LayerNorm over D=512, one wave per position, bf16 out ----------------
__global__ __launch_bounds__(256) void ln_k(const float* __restrict__ x, const float* __restrict__ w,
                                            const float* __restrict__ bv, __bf16* __restrict__ out)
{
  int gw = (blockIdx.x * 256 + threadIdx.x) >> 6;   // position
  int lane = threadIdx.x & 63;
  const float* xp = x + ((size_t)gw << 9) + lane * 8;
  float4 u0 = *(const float4*)xp;
  float4 u1 = *(const float4*)(xp + 4);
  float v[8] = {u0.x,u0.y,u0.z,u0.w,u1.x,u1.y,u1.z,u1.w};
  float s = 0.f;
  #pragma unroll
  for (int j = 0; j < 8; ++j) s += v[j];
  #pragma unroll
  for (int off = 32; off; off >>= 1) s += __shfl_xor(s, off, 64);
  float mu = s * (1.f/512.f);
  float q = 0.f;
  #pragma unroll
  for (int j = 0; j < 8; ++j) { float d = v[j] - mu; q += d*d; }
  #pragma unroll
  for (int off = 32; off; off >>= 1) q += __shfl_xor(q, off, 64);
  float rstd = rsqrtf(q * (1.f/512.f) + 1e-5f);
  int dch = lane * 8;
  float4 w0 = *(const float4*)(w + dch),  w1 = *(const float4*)(w + dch + 4);
  float4 b0 = *(const float4*)(bv + dch), b1 = *(const float4*)(bv + dch + 4);
  float wv[8] = {w0.x,w0.y,w0.z,w0.w,w1.x,w1.y,w1.z,w1.w};
  float bb[8] = {b0.x,b0.y,b0.z,b0.w,b1.x,b1.y,b1.z,b1.w};
  bf16x8 ov;
  #pragma unroll
  for (int j = 0; j < 8; ++j) ov[j] = (__bf16)((v[j] - mu) * rstd * wv[j] + bb[j]);
  *(bf16x8*)(out + ((size_t)gw << 9) + dch) = ov;
}

// ================= Fully-fused conv + 2D scan, 16 ch/block, 2 blocks/CU (R4-proven) =================
__device__ __forceinline__ float sig_a(float al) {
  float a = 1.f / (1.f + expf(-al));
  return fminf(fmaxf(a, 1e-4f), 1.f - 1e-4f);
}

#define CST 544   // chunk stride in elements: 32*16 + 32 pad (1088 B)

__global__ __launch_bounds__(512, 4) void scan2d_k(
    const __bf16* __restrict__ xin, const float* __restrict__ cw, const float* __restrict__ cb,
    const float* __restrict__ alog, const float* __restrict__ bvec, const float* __restrict__ cvec,
    const float* __restrict__ dvec, const __bf16* __restrict__ gate, __bf16* __restrict__ yo)
{
  __shared__ __bf16 T[32 * CST];    // xin tile; partial park in phase C. 34 KB
  __shared__ __bf16 Y[32 * CST];    // u tile. 34 KB
  __shared__ float  S[4][32][16];   // chunk sums: rowF,rowB,colF,colB. 8 KB
  const int tid = threadIdx.x;
  const int bx  = blockIdx.x;
  const int cg  = ((bx & 7) << 2) | (bx >> 3);   // channel group of 16; line-mates same XCD
  const int b   = blockIdx.y;
  const int ch  = tid & 15;
  const int c0  = tid >> 4;         // 0..31; thread owns chunk c0
  const int d   = (cg << 4) + ch;

  const float a   = sig_a(alog[d]);
  const float lna = logf(a);
  const float ia  = 1.f / a;
  const float bb  = bvec[d];
  const float sc  = 0.25f * cvec[d];
  const float dd  = dvec[d];

  const __bf16* ub = xin + ((size_t)b << 19) + (cg << 4);

  // ---- load xin tile: 4 x bf16x8 per thread, 16 B/lane ----
  #pragma unroll
  for (int i = 0; i < 4; ++i) {
    int f = tid + i * 512;          // 16B chunk id, 0..2047
    int pos = f >> 1, half = f & 1;
    *(bf16x8*)(T + (pos >> 5) * CST + ((pos & 31) << 4) + (half << 3))
        = *(const bf16x8*)(ub + (size_t)pos * 512 + (half << 3));
  }
  // conv weights while loads are in flight
  float w00 = cw[(0 << 9) + d], w01 = cw[(1 << 9) + d], w02 = cw[(2 << 9) + d];
  float w10 = cw[(3 << 9) + d], w11 = cw[(4 << 9) + d], w12 = cw[(5 << 9) + d];
  float w20 = cw[(6 << 9) + d], w21 = cw[(7 << 9) + d], w22 = cw[(8 << 9) + d];
  const float cbv = cb[d];
  // scan bases (loop-invariant; direct expf avoids 0*inf at extreme a)
  const float A0f = expf((float)(c0 << 5) * lna),        R0f = expf((float)(c0 << 5) * -lna);
  const float A0b = expf((float)((31 - c0) << 5) * lna), R0b = expf((float)((31 - c0) << 5) * -lna);
  __syncthreads();

  // ---- phase 0: depthwise 3x3 conv + SiLU, row c0 -> Y ----
  {
    const bool up = (c0 > 0);
    const bool dn = (c0 < 31);
    float a0 = 0.f, a1 = 0.f, a2 = 0.f;                                  // col -1
    float b0 = up ? (float)T[(c0 - 1) * CST + ch] : 0.f;                 // col 0
    float b1 =      (float)T[c0 * CST + ch];
    float b2 = dn ? (float)T[(c0 + 1) * CST + ch] : 0.f;
    #pragma unroll 4
    for (int ww = 0; ww < 32; ++ww) {
      float e0 = 0.f, e1 = 0.f, e2 = 0.f;                                // col ww+1
      if (ww < 31) {
        e0 = up ? (float)T[(c0 - 1) * CST + ((ww + 1) << 4) + ch] : 0.f;
        e1 =      (float)T[c0 * CST + ((ww + 1) << 4) + ch];
        e2 = dn ? (float)T[(c0 + 1) * CST + ((ww + 1) << 4) + ch] : 0.f;
      }
      float acc0 = cbv;
      acc0 = fmaf(a0, w00, acc0); acc0 = fmaf(b0, w01, acc0); acc0 = fmaf(e0, w02, acc0);
      acc0 = fmaf(a1, w10, acc0); acc0 = fmaf(b1, w11, acc0); acc0 = fmaf(e1, w12, acc0);
      acc0 = fmaf(a2, w20, acc0); acc0 = fmaf(b2, w21, acc0); acc0 = fmaf(e2, w22, acc0);
      acc0 = acc0 / (1.f + expf(-acc0));
      Y[c0 * CST + (ww << 4) + ch] = (__bf16)acc0;
      a0 = b0; a1 = b1; a2 = b2; b0 = e0; b1 = e1; b2 = e2;
    }
  }
  __syncthreads();

  // one scan step: r += u*bb/max(apr,1e-20) with tracked reciprocal
  #define STEP(r_, uu_, apr_, rp_)                                 \
    { float rr_ = (apr_ < 1e-20f) ? 1e20f : rp_;                   \
      r_ = fmaf((uu_) * bb, rr_, r_); }

  // ---- phase A: 4 chunk sums (rowF/rowB/colF/colB) in one loop ----
  {
    float pf = A0f, qf = R0f, pb = A0b, qb = R0b;
    float s0 = 0.f, s1 = 0.f, s2 = 0.f, s3 = 0.f;
    #pragma unroll 4
    for (int j = 0; j < 32; ++j) {
      float urf = (float)Y[c0 * CST + (j << 4) + ch];
      float urb = (float)Y[c0 * CST + ((31 - j) << 4) + ch];
      float ucf = (float)Y[j * CST + (c0 << 4) + ch];
      float ucb = (float)Y[(31 - j) * CST + (c0 << 4) + ch];
      STEP(s0, urf, pf, qf)  STEP(s2, ucf, pf, qf)
      STEP(s1, urb, pb, qb)  STEP(s3, ucb, pb, qb)
      pf *= a; qf *= ia; pb *= a; qb *= ia;
    }
    S[0][c0][ch] = s0; S[1][c0][ch] = s1; S[2][c0][ch] = s2; S[3][c0][ch] = s3;
  }
  __syncthreads();

  // ---- phase B: exclusive prefix (F arrays) / exclusive suffix (B arrays) ----
  if (tid < 64) {
    int arr = tid >> 4, ch2 = tid & 15;
    float run = 0.f;
    if ((arr & 1) == 0) {
      #pragma unroll 4
      for (int cc = 0; cc < 32; ++cc) { float v = S[arr][cc][ch2]; S[arr][cc][ch2] = run; run += v; }
    } else {
      #pragma unroll 4
      for (int cc = 31; cc >= 0; --cc) { float v = S[arr][cc][ch2]; S[arr][cc][ch2] = run; run += v; }
    }
  }
  __syncthreads();

  // ---- C-col fwd: raw partial -> T  (column c0: pos = j*32+c0 -> chunk j, in-chunk c0) ----
  {
    float r = S[2][c0][ch];
    float p = A0f, q = R0f;
    #pragma unroll 4
    for (int j = 0; j < 32; ++j) {
      int i0 = j * CST + (c0 << 4) + ch;
      float u = (float)Y[i0];
      float ap = fmaxf(p, 1e-20f);
      STEP(r, u, p, q)
      T[i0] = (__bf16)(r * ap);
      p *= a; q *= ia;
    }
  }
  // ---- C-col bwd: T = sc*(T + r*ap)  [same-thread RMW] ----
  {
    float r = S[3][c0][ch];
    float p = A0b, q = R0b;
    #pragma unroll 4
    for (int j = 31; j >= 0; --j) {
      int i0 = j * CST + (c0 << 4) + ch;
      float u = (float)Y[i0];
      float ap = fmaxf(p, 1e-20f);
      STEP(r, u, p, q)
      T[i0] = (__bf16)(sc * ((float)T[i0] + r * ap));
      p *= a; q *= ia;
    }
  }
  __syncthreads();   // row threads read other threads' col finals

  // ---- C-row fwd: T += sc*(r*ap)  (row c0: chunk c0, in-chunk j) ----
  {
    float r = S[0][c0][ch];
    float p = A0f, q = R0f;
    #pragma unroll 4
    for (int j = 0; j < 32; ++j) {
      int i0 = c0 * CST + (j << 4) + ch;
      float u = (float)Y[i0];
      float ap = fmaxf(p, 1e-20f);
      STEP(r, u, p, q)
      T[i0] = (__bf16)((float)T[i0] + sc * (r * ap));
      p *= a; q *= ia;
    }
  }
  // ---- C-row bwd: finalize + d*u, *gate, write out ----
  {
    const __bf16* gb = gate + ((size_t)b << 19) + (cg << 4) + ch;
    __bf16* yb = yo + ((size_t)b << 19) + (cg << 4) + ch;
    float r = S[1][c0][ch];
    float p = A0b, q = R0b;
    #pragma unroll 4
    for (int j = 31; j >= 0; --j) {
      int pp = (c0 << 5) + j;
      int i0 = c0 * CST + (j << 4) + ch;
      float u = (float)Y[i0];
      float ap = fmaxf(p, 1e-20f);
      STEP(r, u, p, q)
      float y0 = (float)T[i0] + sc * (r * ap) + dd * u;
      yb[(size_t)pp * 512] = (__bf16)(y0 * (float)gb[(size_t)pp * 512]);
      p *= a; q *= ia;
    }
  }
  #undef STEP
}

// ---------------- mean over 1024 positions (bf16 in) -> (16, 512) fp32 ----------------
__global__ __launch_bounds__(256) void reduce_k(const __bf16* __restrict__ hn, float* __restrict__ out)
{
  __shared__ float part[4][64];
  int l = threadIdx.x & 63;       // channel within group
  int q = threadIdx.x >> 6;       // position quarter
  int d = blockIdx.y * 64 + l;
  int b = blockIdx.x;
  const __bf16* p = hn + ((size_t)b << 19) + d + ((size_t)(q * 256) << 9);
  float s0 = 0.f, s1 = 0.f, s2 = 0.f, s3 = 0.f;
  for (int t = 0; t < 256; t += 4) {
    s0 += (float)p[(size_t)(t+0) << 9];
    s1 += (float)p[(size_t)(t+1) << 9];
    s2 += (float)p[(size_t)(t+2) << 9];
    s3 += (float)p[(size_t)(t+3) << 9];
  }
  part[q][l] = (s0 + s1) + (s2 + s3);
  __syncthreads();
  if (threadIdx.x < 64)
    out[b * 512 + d] = (part[0][l] + part[1][l] + part[2][l] + part[3][l]) * (1.f / 1024.f);
}

extern "C" void kernel_launch(void* const* d_in, const int* in_sizes, int n_in,
                              void* d_out, int out_size, void* d_ws, size_t ws_size,
                              hipStream_t stream)
{
  const float* tokens = (const float*)d_in[0];
  const float* in_w   = (const float*)d_in[1];
  const float* in_b   = (const float*)d_in[2];
  const float* nw     = (const float*)d_in[3];
  const float* nb     = (const float*)d_in[4];
  const float* iw     = (const float*)d_in[5];
  const float* ib     = (const float*)d_in[6];
  const float* cw     = (const float*)d_in[7];
  const float* cb     = (const float*)d_in[8];
  const float* al     = (const float*)d_in[9];
  const float* bbv    = (const float*)d_in[10];
  const float* ccv    = (const float*)d_in[11];
  const float* ddv    = (const float*)d_in[12];
  const float* ow     = (const float*)d_in[13];
  const float* obv    = (const float*)d_in[14];
  const float* onw    = (const float*)d_in[15];
  const float* onb    = (const float*)d_in[16];

  // workspace layout (~115 MB):
  float*  x     = (float*)d_ws;                      // fp32 residual (33.5 MB)
  __bf16* hy16  = (__bf16*)(x + PP);                 // bf16 h / yg / final-ln (16.8 MB)
  __bf16* xin16 = hy16 + PP;                         // bf16 x_in (16.8 MB)
  __bf16* g16   = xin16 + PP;                        // bf16 gate (16.8 MB)
  __bf16* iwT   = g16 + PP;                          // 4x(1024x512) bf16 (4.2 MB)
  __bf16* owT   = iwT + (size_t)4 * 1024 * 512;      // 4x(512x512) bf16 (2.1 MB)
  __bf16* tb16  = owT + (size_t)4 * 512 * 512;       // tokens bf16 (25.2 MB)
  __bf16* inwT  = xin16;                             // in_proj_w^T bf16 (pre-loop alias)

  // --- weight/input conversion (once per launch) ---
  cvt_k<<<6144, 256, 0, stream>>>(tokens, tb16);
  tr_k<<<dim3(16, 24, 1), 256, 0, stream>>>(in_w, inwT, 768, 512, 0, 0);
  tr_k<<<dim3(32, 16, 4), 256, 0, stream>>>(iw, iwT, 512, 1024, (size_t)512*1024, (size_t)1024*512);
  tr_k<<<dim3(16, 16, 4), 256, 0, stream>>>(ow, owT, 512, 512, (size_t)512*512, (size_t)512*512);

  // x = tokens @ in_proj_w + b   (128 M-tiles x 4 N-tiles = 512 blocks; R5-proven)
  gemm_k<0><<<512, 512, 0, stream>>>(tb16, inwT, in_b, nullptr, x, nullptr, nullptr,
                                     512, 768, 0);

  for (int i = 0; i < 4; ++i) {
    ln_k<<<4096, 256, 0, stream>>>(x, nw + i*512, nb + i*512, hy16);
    // (h @ iw + ib): 128 M x 4 N (256-wide) = 512 blocks, 72KB -> 2/CU, no tail
    gemm_k<1><<<512, 512, 0, stream>>>(hy16, iwT + (size_t)i*1024*512, ib + i*1024,
                                       nullptr, nullptr, g16, xin16, 1024, 512, 1);
    // 32 ch-groups x 16 batch = 512 blocks, 2/CU
    scan2d_k<<<dim3(32, 16), 512, 0, stream>>>(xin16, cw + i*9*512, cb + i*512,
                                               al + i*512, bbv + i*512, ccv + i*512,
                                               ddv + i*512, g16, hy16);
    // (yg @ ow + ob + x): 128 x 4 = 512 blocks (R5-proven)
    gemm_k<0><<<512, 512, 0, stream>>>(hy16, owT + (size_t)i*512*512, obv + i*512,
                                       x, x, nullptr, nullptr, 512, 512, 2);
  }

  ln_k<<<4096, 256, 0, stream>>>(x, onw, onb, hy16);
  reduce_k<<<dim3(16, 8), 256, 0, stream>>>(hy16, (float*)d_out);
}

// Round 10
// 542.093 us; speedup vs baseline: 1.2535x; 1.0446x over previous
//
#include <hip/hip_runtime.h>
#include <hip/hip_bf16.h>
#include <math.h>

#define NPOS 16384   // B*H*W = 16*32*32
#define DD   512
#define PP   ((size_t)NPOS * DD)   // 8388608 elements per plane

typedef __bf16 bf16x8 __attribute__((ext_vector_type(8)));
typedef float  f32x4  __attribute__((ext_vector_type(4)));

// ---- async global->LDS, 16B per lane (global_load_lds_dwordx4) ----
__device__ __forceinline__ void gload16(const __bf16* g, __bf16* l) {
  __builtin_amdgcn_global_load_lds((__attribute__((address_space(1))) void*)(g),
                                   (__attribute__((address_space(3))) void*)(l), 16, 0, 0);
}
__device__ __forceinline__ void wait_vm0() { asm volatile("s_waitcnt vmcnt(0)" ::: "memory"); }
__device__ __forceinline__ void wait_vm2() { asm volatile("s_waitcnt vmcnt(2)" ::: "memory"); }
__device__ __forceinline__ void wait_lgkm0() { asm volatile("s_waitcnt lgkmcnt(0)" ::: "memory"); }

// ================= bf16 MFMA GEMM, 128x128 all-LDS, two residency flavors =================
// Ledger: B-direct-from-L2 ✗✗ (R7 depth-1, R8 depth-2); 256^2 @1/CU ✗ (R1); 128x256
// @2/CU ✗ (R9: LDS-bytes/MFMA -31% lost to occupancy 24->16 waves/CU). Model: keep
// all-LDS 128^2 and MAXIMIZE residency.
// EP1=1 (epi1, 1024-block grid): ring-2 (A 16KB + B 16KB = 32KB staging; 40KB block
//   for the epilogue shuffle) -> LDS-limit 4 blocks/CU, wave-limit 32/8 = 4 ->
//   4 blocks/CU: ALL 1024 blocks resident in one round (R5 had 3/CU = 768 + 256
//   ragged tail), 32 waves/CU. vmcnt(0) per tile (m97 double-buffer structure);
//   4 co-resident blocks cover the drain (R3/R4-verified cross-block overlap).
// EP1=0 (epi0/epi2, 512-block grids): byte-exact R5 loop - ring-3 48KB, counted
//   vmcnt(2), fp32 direct full-line epilogue. Measured-good (535.8us total).
// Both: global-side XOR swizzle (c ^ ((row>>1)&3)) -> conflict-free frag ds_read_b128
// (rule 21); s_setprio around MFMA; ONE barrier per K-tile; bijective XCD swizzle with
// ntc fastest (A-sharers same XCD).
// epi 0: C0 fp32 (ld N) = acc + bias
// epi 1: N=1024; bn<512 -> C1b bf16 (ld 512); bn>=512 -> sigmoid -> C1 bf16 (ld 512)
//        (full-line bf16 epilogue via per-wave LDS shuffle, 64 rows x 80B)
// epi 2: C0 fp32 (ld N) = acc + bias + res
template<int EP1>
__global__ __launch_bounds__(512, 4) void gemm_k(
    const __bf16* __restrict__ A, const __bf16* __restrict__ Bt,
    const float* __restrict__ bias, const float* __restrict__ res,
    float* __restrict__ C0, __bf16* __restrict__ C1, __bf16* __restrict__ C1b,
    int N, int K, int epi)
{
  __shared__ __bf16 SM[EP1 ? 20480 : 24576];               // 40 KB / 48 KB
  __bf16 (*Asm)[4096] = (__bf16(*)[4096])SM;               // ring bufs, 8 KB each
  __bf16 (*Bsm)[4096] = (__bf16(*)[4096])(SM + (EP1 ? 8192 : 12288));

  const int tid  = threadIdx.x;
  const int w    = tid >> 6;
  const int lane = tid & 63;
  const int quad = lane >> 4;
  const int l16  = lane & 15;
  const int wm   = (w >> 2) << 6;       // 2 M-waves x 64 rows
  const int wn   = (w & 3) << 5;        // 4 N-waves x 32 cols

  // grid decode: bijective XCD swizzle, then ntc fastest (A-sharers adjacent per XCD)
  const int nwg = gridDim.x;
  const int cpx = nwg >> 3;
  const int lin = (blockIdx.x & 7) * cpx + (blockIdx.x >> 3);
  const int nbn = N >> 7;               // 128-wide N tiles (4 or 8)
  const int sh  = (nbn == 8) ? 3 : 2;
  const int mt  = lin >> sh;
  const int ntc = lin & (nbn - 1);
  const int bm  = mt << 7;
  const int bn  = ntc << 7;

  const __bf16* Ab = A  + (size_t)bm * K;
  const __bf16* Bb = Bt + (size_t)bn * K;
  const int nk = K >> 5;

  f32x4 acc[4][2];
  #pragma unroll
  for (int i = 0; i < 4; ++i)
    #pragma unroll
    for (int j = 0; j < 2; ++j) acc[i][j] = (f32x4){0.f, 0.f, 0.f, 0.f};

  // staging: 512 threads x 16B = whole 128x32 tile per load. LDS lane-linear
  // (gload_lds requirement); global col-chunk pre-swizzled so swizzled frag reads see
  // linear data (rule 21): LDS[r][sl] = G[r][sl ^ ((r>>1)&3)].
  #define STG_A(tile, buf) {                                                     \
    const int r_ = tid >> 2, c_ = tid & 3;                                       \
    gload16(Ab + (size_t)r_ * K + ((tile) << 5) + ((c_ ^ ((r_ >> 1) & 3)) << 3), \
            &Asm[buf][tid << 3]);                                                \
  }
  #define STG_B(tile, buf) {                                                     \
    const int r_ = tid >> 2, c_ = tid & 3;                                       \
    gload16(Bb + (size_t)r_ * K + ((tile) << 5) + ((c_ ^ ((r_ >> 1) & 3)) << 3), \
            &Bsm[buf][tid << 3]);                                                \
  }

  int cur = 0;
  if constexpr (EP1 == 0) {
    // ---------- R5-proven loop: A+B LDS ring-3, counted vmcnt(2) ----------
    STG_A(0, 0) STG_B(0, 0)
    STG_A(1, 1) STG_B(1, 1)
    wait_vm2();
    __builtin_amdgcn_s_barrier();

    for (int t = 0; t < nk; ++t) {
      const int nx2 = (cur == 0) ? 2 : cur - 1;
      const bool st = (t + 2 < nk);
      if (st) {
        STG_A(t + 2, nx2)
        STG_B(t + 2, nx2)
      }
      bf16x8 af[4], bfr[2];
      #pragma unroll
      for (int i = 0; i < 4; ++i) {
        const int m = wm + i * 16 + l16;
        af[i] = *(const bf16x8*)(&Asm[cur][m * 32 + ((quad ^ ((m >> 1) & 3)) << 3)]);
      }
      #pragma unroll
      for (int j = 0; j < 2; ++j) {
        const int n = wn + j * 16 + l16;
        bfr[j] = *(const bf16x8*)(&Bsm[cur][n * 32 + ((quad ^ ((n >> 1) & 3)) << 3)]);
      }
      __builtin_amdgcn_s_setprio(1);
      #pragma unroll
      for (int i = 0; i < 4; ++i) {
        acc[i][0] = __builtin_amdgcn_mfma_f32_16x16x32_bf16(af[i], bfr[0], acc[i][0], 0, 0, 0);
        acc[i][1] = __builtin_amdgcn_mfma_f32_16x16x32_bf16(af[i], bfr[1], acc[i][1], 0, 0, 0);
      }
      __builtin_amdgcn_s_setprio(0);
      if (st) { wait_vm2(); } else { wait_vm0(); }
      __builtin_amdgcn_s_barrier();
      cur = (cur == 2) ? 0 : cur + 1;
    }
  } else {
    // ---------- ring-2 (m97 double-buffer): 32KB staging -> 4 blocks/CU ----------
    STG_A(0, 0) STG_B(0, 0)
    wait_vm0();
    __builtin_amdgcn_s_barrier();

    for (int t = 0; t < nk; ++t) {
      const bool st = (t + 1 < nk);
      // stage t+1 into cur^1 FIRST (full tile of MFMA time to land; cur^1's readers
      // all finished at the t-1 end barrier)
      if (st) {
        STG_A(t + 1, cur ^ 1)
        STG_B(t + 1, cur ^ 1)
      }
      bf16x8 af[4], bfr[2];
      #pragma unroll
      for (int i = 0; i < 4; ++i) {
        const int m = wm + i * 16 + l16;
        af[i] = *(const bf16x8*)(&Asm[cur][m * 32 + ((quad ^ ((m >> 1) & 3)) << 3)]);
      }
      #pragma unroll
      for (int j = 0; j < 2; ++j) {
        const int n = wn + j * 16 + l16;
        bfr[j] = *(const bf16x8*)(&Bsm[cur][n * 32 + ((quad ^ ((n >> 1) & 3)) << 3)]);
      }
      __builtin_amdgcn_s_setprio(1);
      #pragma unroll
      for (int i = 0; i < 4; ++i) {
        acc[i][0] = __builtin_amdgcn_mfma_f32_16x16x32_bf16(af[i], bfr[0], acc[i][0], 0, 0, 0);
        acc[i][1] = __builtin_amdgcn_mfma_f32_16x16x32_bf16(af[i], bfr[1], acc[i][1], 0, 0, 0);
      }
      __builtin_amdgcn_s_setprio(0);
      if (st) wait_vm0();
      __builtin_amdgcn_s_barrier();   // unconditional: also fences epilogue LDS reuse
      cur ^= 1;
    }
  }
  #undef STG_A
  #undef STG_B

  // ---- epilogue. C/D layout: col = lane&15, row = quad*4 + reg  [m89-verified] ----
  if constexpr (EP1) {
    // full-line bf16 path: scatter through per-wave LDS (64 rows x 80B stride; 8 waves
    // x 5120B = 40KB), read back bf16x8 -> 16B/lane stores; full 64B lines.
    const bool dosig = (bn >= 512);
    __bf16* dst = dosig ? C1 : C1b;
    const int cb = dosig ? (bn - 512) : bn;
    char* wb = (char*)SM + w * 5120;
    #pragma unroll
    for (int i = 0; i < 4; ++i)
      #pragma unroll
      for (int j = 0; j < 2; ++j) {
        const float bv = bias[bn + wn + j * 16 + l16];
        #pragma unroll
        for (int r = 0; r < 4; ++r) {
          float v = acc[i][j][r] + bv;
          if (dosig) v = 1.f / (1.f + expf(-v));
          *(__bf16*)(wb + (i * 16 + quad * 4 + r) * 80 + (j * 16 + l16) * 2) = (__bf16)v;
        }
      }
    wait_lgkm0();                                 // wave-local; no barrier needed
    #pragma unroll
    for (int s = 0; s < 4; ++s) {
      const int rr = s * 16 + (lane >> 2);        // 0..63 within wave tile
      bf16x8 vv = *(bf16x8*)(wb + rr * 80 + (lane & 3) * 16);
      const int grow = bm + wm + rr;
      *(bf16x8*)(dst + (size_t)grow * 512 + cb + wn + (lane & 3) * 8) = vv;
    }
  } else {
    // fp32 path: 16 lanes x 4B = full 64B line per store group already
    #pragma unroll
    for (int j = 0; j < 2; ++j) {
      const int col = wn + j * 16 + l16;
      const float bv = bias[bn + col];
      #pragma unroll
      for (int i = 0; i < 4; ++i) {
        const int row0 = bm + wm + i * 16 + quad * 4;
        #pragma unroll
        for (int r = 0; r < 4; ++r) {
          float v = acc[i][j][r] + bv;
          size_t off = (size_t)(row0 + r) * N + bn + col;
          if (epi == 2) v += res[off];
          C0[off] = v;
        }
      }
    }
  }
}

// ---------------- fp32 -> bf16 elementwise (tokens) ----------------
__global__ __launch_bounds__(256) void cvt_k(const float* __restrict__ s, __bf16* __restrict__ d)
{
  size_t i = ((size_t)blockIdx.x * 256 + threadIdx.x) * 8;
  float4 a = *(const float4*)(s + i);
  float4 b = *(const float4*)(s + i + 4);
  bf16x8 v;
  v[0] = (__bf16)a.x; v[1] = (__bf16)a.y; v[2] = (__bf16)a.z; v[3] = (__bf16)a.w;
  v[4] = (__bf16)b.x; v[5] = (__bf16)b.y; v[6] = (__bf16)b.z; v[7] = (__bf16)b.w;
  *(bf16x8*)(d + i) = v;
}

// ---------------- transpose KxN fp32 -> NxK bf16 (weights) ----------------
__global__ __launch_bounds__(256) void tr_k(const float* __restrict__ src, __bf16* __restrict__ dst,
                                            int K, int N, size_t sstr, size_t dstr)
{
  __shared__ float t[32][33];
  const float* s = src + blockIdx.z * sstr;
  __bf16* d = dst + blockIdx.z * dstr;
  int n0 = blockIdx.x * 32, k0 = blockIdx.y * 32;
  int tx = threadIdx.x & 31, ty = threadIdx.x >> 5;   // 32x8
  #pragma unroll
  for (int i = 0; i < 4; ++i)
    t[ty + i * 8][tx] = s[(size_t)(k0 + ty + i * 8) * N + n0 + tx];
  __syncthreads();
  #pragma unroll
  for (int i = 0; i < 4; ++i)
    d[(size_t)(n0 + ty + i * 8) * K + k0 + tx] = (__bf16)t[tx][ty + i * 8];
}

// ---------------- LayerNorm over D=512, one wave per position, bf16 out ----------------
__global__ __launch_bounds__(256) void ln_k(const float* __restrict__ x, const float* __restrict__ w,
                                            const float* __restrict__ bv, __bf16* __restrict__ out)
{
  int gw = (blockIdx.x * 256 + threadIdx.x) >> 6;   // position
  int lane = threadIdx.x & 63;
  const float* xp = x + ((size_t)gw << 9) + lane * 8;
  float4 u0 = *(const float4*)xp;
  float4 u1 = *(const float4*)(xp + 4);
  float v[8] = {u0.x,u0.y,u0.z,u0.w,u1.x,u1.y,u1.z,u1.w};
  float s = 0.f;
  #pragma unroll
  for (int j = 0; j < 8; ++j) s += v[j];
  #pragma unroll
  for (int off = 32; off; off >>= 1) s += __shfl_xor(s, off, 64);
  float mu = s * (1.f/512.f);
  float q = 0.f;
  #pragma unroll
  for (int j = 0; j < 8; ++j) { float d = v[j] - mu; q += d*d; }
  #pragma unroll
  for (int off = 32; off; off >>= 1) q += __shfl_xor(q, off, 64);
  float rstd = rsqrtf(q * (1.f/512.f) + 1e-5f);
  int dch = lane * 8;
  float4 w0 = *(const float4*)(w + dch),  w1 = *(const float4*)(w + dch + 4);
  float4 b0 = *(const float4*)(bv + dch), b1 = *(const float4*)(bv + dch + 4);
  float wv[8] = {w0.x,w0.y,w0.z,w0.w,w1.x,w1.y,w1.z,w1.w};
  float bb[8] = {b0.x,b0.y,b0.z,b0.w,b1.x,b1.y,b1.z,b1.w};
  bf16x8 ov;
  #pragma unroll
  for (int j = 0; j < 8; ++j) ov[j] = (__bf16)((v[j] - mu) * rstd * wv[j] + bb[j]);
  *(bf16x8*)(out + ((size_t)gw << 9) + dch) = ov;
}

// ================= Fully-fused conv + 2D scan, 16 ch/block, 2 blocks/CU (R4-proven) =================
__device__ __forceinline__ float sig_a(float al) {
  float a = 1.f / (1.f + expf(-al));
  return fminf(fmaxf(a, 1e-4f), 1.f - 1e-4f);
}

#define CST 544   // chunk stride in elements: 32*16 + 32 pad (1088 B)

__global__ __launch_bounds__(512, 4) void scan2d_k(
    const __bf16* __restrict__ xin, const float* __restrict__ cw, const float* __restrict__ cb,
    const float* __restrict__ alog, const float* __restrict__ bvec, const float* __restrict__ cvec,
    const float* __restrict__ dvec, const __bf16* __restrict__ gate, __bf16* __restrict__ yo)
{
  __shared__ __bf16 T[32 * CST];    // xin tile; partial park in phase C. 34 KB
  __shared__ __bf16 Y[32 * CST];    // u tile. 34 KB
  __shared__ float  S[4][32][16];   // chunk sums: rowF,rowB,colF,colB. 8 KB
  const int tid = threadIdx.x;
  const int bx  = blockIdx.x;
  const int cg  = ((bx & 7) << 2) | (bx >> 3);   // channel group of 16; line-mates same XCD
  const int b   = blockIdx.y;
  const int ch  = tid & 15;
  const int c0  = tid >> 4;         // 0..31; thread owns chunk c0
  const int d   = (cg << 4) + ch;

  const float a   = sig_a(alog[d]);
  const float lna = logf(a);
  const float ia  = 1.f / a;
  const float bb  = bvec[d];
  const float sc  = 0.25f * cvec[d];
  const float dd  = dvec[d];

  const __bf16* ub = xin + ((size_t)b << 19) + (cg << 4);

  // ---- load xin tile: 4 x bf16x8 per thread, 16 B/lane ----
  #pragma unroll
  for (int i = 0; i < 4; ++i) {
    int f = tid + i * 512;          // 16B chunk id, 0..2047
    int pos = f >> 1, half = f & 1;
    *(bf16x8*)(T + (pos >> 5) * CST + ((pos & 31) << 4) + (half << 3))
        = *(const bf16x8*)(ub + (size_t)pos * 512 + (half << 3));
  }
  // conv weights while loads are in flight
  float w00 = cw[(0 << 9) + d], w01 = cw[(1 << 9) + d], w02 = cw[(2 << 9) + d];
  float w10 = cw[(3 << 9) + d], w11 = cw[(4 << 9) + d], w12 = cw[(5 << 9) + d];
  float w20 = cw[(6 << 9) + d], w21 = cw[(7 << 9) + d], w22 = cw[(8 << 9) + d];
  const float cbv = cb[d];
  // scan bases (loop-invariant; direct expf avoids 0*inf at extreme a)
  const float A0f = expf((float)(c0 << 5) * lna),        R0f = expf((float)(c0 << 5) * -lna);
  const float A0b = expf((float)((31 - c0) << 5) * lna), R0b = expf((float)((31 - c0) << 5) * -lna);
  __syncthreads();

  // ---- phase 0: depthwise 3x3 conv + SiLU, row c0 -> Y ----
  {
    const bool up = (c0 > 0);
    const bool dn = (c0 < 31);
    float a0 = 0.f, a1 = 0.f, a2 = 0.f;                                  // col -1
    float b0 = up ? (float)T[(c0 - 1) * CST + ch] : 0.f;                 // col 0
    float b1 =      (float)T[c0 * CST + ch];
    float b2 = dn ? (float)T[(c0 + 1) * CST + ch] : 0.f;
    #pragma unroll 4
    for (int ww = 0; ww < 32; ++ww) {
      float e0 = 0.f, e1 = 0.f, e2 = 0.f;                                // col ww+1
      if (ww < 31) {
        e0 = up ? (float)T[(c0 - 1) * CST + ((ww + 1) << 4) + ch] : 0.f;
        e1 =      (float)T[c0 * CST + ((ww + 1) << 4) + ch];
        e2 = dn ? (float)T[(c0 + 1) * CST + ((ww + 1) << 4) + ch] : 0.f;
      }
      float acc0 = cbv;
      acc0 = fmaf(a0, w00, acc0); acc0 = fmaf(b0, w01, acc0); acc0 = fmaf(e0, w02, acc0);
      acc0 = fmaf(a1, w10, acc0); acc0 = fmaf(b1, w11, acc0); acc0 = fmaf(e1, w12, acc0);
      acc0 = fmaf(a2, w20, acc0); acc0 = fmaf(b2, w21, acc0); acc0 = fmaf(e2, w22, acc0);
      acc0 = acc0 / (1.f + expf(-acc0));
      Y[c0 * CST + (ww << 4) + ch] = (__bf16)acc0;
      a0 = b0; a1 = b1; a2 = b2; b0 = e0; b1 = e1; b2 = e2;
    }
  }
  __syncthreads();

  // one scan step: r += u*bb/max(apr,1e-20) with tracked reciprocal
  #define STEP(r_, uu_, apr_, rp_)                                 \
    { float rr_ = (apr_ < 1e-20f) ? 1e20f : rp_;                   \
      r_ = fmaf((uu_) * bb, rr_, r_); }

  // ---- phase A: 4 chunk sums (rowF/rowB/colF/colB) in one loop ----
  {
    float pf = A0f, qf = R0f, pb = A0b, qb = R0b;
    float s0 = 0.f, s1 = 0.f, s2 = 0.f, s3 = 0.f;
    #pragma unroll 4
    for (int j = 0; j < 32; ++j) {
      float urf = (float)Y[c0 * CST + (j << 4) + ch];
      float urb = (float)Y[c0 * CST + ((31 - j) << 4) + ch];
      float ucf = (float)Y[j * CST + (c0 << 4) + ch];
      float ucb = (float)Y[(31 - j) * CST + (c0 << 4) + ch];
      STEP(s0, urf, pf, qf)  STEP(s2, ucf, pf, qf)
      STEP(s1, urb, pb, qb)  STEP(s3, ucb, pb, qb)
      pf *= a; qf *= ia; pb *= a; qb *= ia;
    }
    S[0][c0][ch] = s0; S[1][c0][ch] = s1; S[2][c0][ch] = s2; S[3][c0][ch] = s3;
  }
  __syncthreads();

  // ---- phase B: exclusive prefix (F arrays) / exclusive suffix (B arrays) ----
  if (tid < 64) {
    int arr = tid >> 4, ch2 = tid & 15;
    float run = 0.f;
    if ((arr & 1) == 0) {
      #pragma unroll 4
      for (int cc = 0; cc < 32; ++cc) { float v = S[arr][cc][ch2]; S[arr][cc][ch2] = run; run += v; }
    } else {
      #pragma unroll 4
      for (int cc = 31; cc >= 0; --cc) { float v = S[arr][cc][ch2]; S[arr][cc][ch2] = run; run += v; }
    }
  }
  __syncthreads();

  // ---- C-col fwd: raw partial -> T  (column c0: pos = j*32+c0 -> chunk j, in-chunk c0) ----
  {
    float r = S[2][c0][ch];
    float p = A0f, q = R0f;
    #pragma unroll 4
    for (int j = 0; j < 32; ++j) {
      int i0 = j * CST + (c0 << 4) + ch;
      float u = (float)Y[i0];
      float ap = fmaxf(p, 1e-20f);
      STEP(r, u, p, q)
      T[i0] = (__bf16)(r * ap);
      p *= a; q *= ia;
    }
  }
  // ---- C-col bwd: T = sc*(T + r*ap)  [same-thread RMW] ----
  {
    float r = S[3][c0][ch];
    float p = A0b, q = R0b;
    #pragma unroll 4
    for (int j = 31; j >= 0; --j) {
      int i0 = j * CST + (c0 << 4) + ch;
      float u = (float)Y[i0];
      float ap = fmaxf(p, 1e-20f);
      STEP(r, u, p, q)
      T[i0] = (__bf16)(sc * ((float)T[i0] + r * ap));
      p *= a; q *= ia;
    }
  }
  __syncthreads();   // row threads read other threads' col finals

  // ---- C-row fwd: T += sc*(r*ap)  (row c0: chunk c0, in-chunk j) ----
  {
    float r = S[0][c0][ch];
    float p = A0f, q = R0f;
    #pragma unroll 4
    for (int j = 0; j < 32; ++j) {
      int i0 = c0 * CST + (j << 4) + ch;
      float u = (float)Y[i0];
      float ap = fmaxf(p, 1e-20f);
      STEP(r, u, p, q)
      T[i0] = (__bf16)((float)T[i0] + sc * (r * ap));
      p *= a; q *= ia;
    }
  }
  // ---- C-row bwd: finalize + d*u, *gate, write out ----
  {
    const __bf16* gb = gate + ((size_t)b << 19) + (cg << 4) + ch;
    __bf16* yb = yo + ((size_t)b << 19) + (cg << 4) + ch;
    float r = S[1][c0][ch];
    float p = A0b, q = R0b;
    #pragma unroll 4
    for (int j = 31; j >= 0; --j) {
      int pp = (c0 << 5) + j;
      int i0 = c0 * CST + (j << 4) + ch;
      float u = (float)Y[i0];
      float ap = fmaxf(p, 1e-20f);
      STEP(r, u, p, q)
      float y0 = (float)T[i0] + sc * (r * ap) + dd * u;
      yb[(size_t)pp * 512] = (__bf16)(y0 * (float)gb[(size_t)pp * 512]);
      p *= a; q *= ia;
    }
  }
  #undef STEP
}

// ---------------- mean over 1024 positions (bf16 in) -> (16, 512) fp32 ----------------
__global__ __launch_bounds__(256) void reduce_k(const __bf16* __restrict__ hn, float* __restrict__ out)
{
  __shared__ float part[4][64];
  int l = threadIdx.x & 63;       // channel within group
  int q = threadIdx.x >> 6;       // position quarter
  int d = blockIdx.y * 64 + l;
  int b = blockIdx.x;
  const __bf16* p = hn + ((size_t)b << 19) + d + ((size_t)(q * 256) << 9);
  float s0 = 0.f, s1 = 0.f, s2 = 0.f, s3 = 0.f;
  for (int t = 0; t < 256; t += 4) {
    s0 += (float)p[(size_t)(t+0) << 9];
    s1 += (float)p[(size_t)(t+1) << 9];
    s2 += (float)p[(size_t)(t+2) << 9];
    s3 += (float)p[(size_t)(t+3) << 9];
  }
  part[q][l] = (s0 + s1) + (s2 + s3);
  __syncthreads();
  if (threadIdx.x < 64)
    out[b * 512 + d] = (part[0][l] + part[1][l] + part[2][l] + part[3][l]) * (1.f / 1024.f);
}

extern "C" void kernel_launch(void* const* d_in, const int* in_sizes, int n_in,
                              void* d_out, int out_size, void* d_ws, size_t ws_size,
                              hipStream_t stream)
{
  const float* tokens = (const float*)d_in[0];
  const float* in_w   = (const float*)d_in[1];
  const float* in_b   = (const float*)d_in[2];
  const float* nw     = (const float*)d_in[3];
  const float* nb     = (const float*)d_in[4];
  const float* iw     = (const float*)d_in[5];
  const float* ib     = (const float*)d_in[6];
  const float* cw     = (const float*)d_in[7];
  const float* cb     = (const float*)d_in[8];
  const float* al     = (const float*)d_in[9];
  const float* bbv    = (const float*)d_in[10];
  const float* ccv    = (const float*)d_in[11];
  const float* ddv    = (const float*)d_in[12];
  const float* ow     = (const float*)d_in[13];
  const float* obv    = (const float*)d_in[14];
  const float* onw    = (const float*)d_in[15];
  const float* onb    = (const float*)d_in[16];

  // workspace layout (~115 MB):
  float*  x     = (float*)d_ws;                      // fp32 residual (33.5 MB)
  __bf16* hy16  = (__bf16*)(x + PP);                 // bf16 h / yg / final-ln (16.8 MB)
  __bf16* xin16 = hy16 + PP;                         // bf16 x_in (16.8 MB)
  __bf16* g16   = xin16 + PP;                        // bf16 gate (16.8 MB)
  __bf16* iwT   = g16 + PP;                          // 4x(1024x512) bf16 (4.2 MB)
  __bf16* owT   = iwT + (size_t)4 * 1024 * 512;      // 4x(512x512) bf16 (2.1 MB)
  __bf16* tb16  = owT + (size_t)4 * 512 * 512;       // tokens bf16 (25.2 MB)
  __bf16* inwT  = xin16;                             // in_proj_w^T bf16 (pre-loop alias)

  // --- weight/input conversion (once per launch) ---
  cvt_k<<<6144, 256, 0, stream>>>(tokens, tb16);
  tr_k<<<dim3(16, 24, 1), 256, 0, stream>>>(in_w, inwT, 768, 512, 0, 0);
  tr_k<<<dim3(32, 16, 4), 256, 0, stream>>>(iw, iwT, 512, 1024, (size_t)512*1024, (size_t)1024*512);
  tr_k<<<dim3(16, 16, 4), 256, 0, stream>>>(ow, owT, 512, 512, (size_t)512*512, (size_t)512*512);

  // x = tokens @ in_proj_w + b   (128 M-tiles x 4 N-tiles = 512 blocks; R5-proven)
  gemm_k<0><<<512, 512, 0, stream>>>(tb16, inwT, in_b, nullptr, x, nullptr, nullptr,
                                     512, 768, 0);

  for (int i = 0; i < 4; ++i) {
    ln_k<<<4096, 256, 0, stream>>>(x, nw + i*512, nb + i*512, hy16);
    // (h @ iw + ib): 128 x 8 = 1024 blocks, 40KB ring-2 -> 4 blocks/CU, no tail
    gemm_k<1><<<1024, 512, 0, stream>>>(hy16, iwT + (size_t)i*1024*512, ib + i*1024,
                                        nullptr, nullptr, g16, xin16, 1024, 512, 1);
    // 32 ch-groups x 16 batch = 512 blocks, 2/CU
    scan2d_k<<<dim3(32, 16), 512, 0, stream>>>(xin16, cw + i*9*512, cb + i*512,
                                               al + i*512, bbv + i*512, ccv + i*512,
                                               ddv + i*512, g16, hy16);
    // (yg @ ow + ob + x): 128 x 4 = 512 blocks (R5-proven)
    gemm_k<0><<<512, 512, 0, stream>>>(hy16, owT + (size_t)i*512*512, obv + i*512,
                                       x, x, nullptr, nullptr, 512, 512, 2);
  }

  ln_k<<<4096, 256, 0, stream>>>(x, onw, onb, hy16);
  reduce_k<<<dim3(16, 8), 256, 0, stream>>>(hy16, (float*)d_out);
}

// Round 11
// 535.774 us; speedup vs baseline: 1.2683x; 1.0118x over previous
//
#include <hip/hip_runtime.h>
#include <hip/hip_bf16.h>
#include <math.h>

#define NPOS 16384   // B*H*W = 16*32*32
#define DD   512
#define PP   ((size_t)NPOS * DD)   // 8388608 elements per plane

typedef __bf16 bf16x8 __attribute__((ext_vector_type(8)));
typedef float  f32x4  __attribute__((ext_vector_type(4)));

// ---- async global->LDS, 16B per lane (global_load_lds_dwordx4) ----
__device__ __forceinline__ void gload16(const __bf16* g, __bf16* l) {
  __builtin_amdgcn_global_load_lds((__attribute__((address_space(1))) void*)(g),
                                   (__attribute__((address_space(3))) void*)(l), 16, 0, 0);
}
__device__ __forceinline__ void wait_vm0() { asm volatile("s_waitcnt vmcnt(0)" ::: "memory"); }
__device__ __forceinline__ void wait_vm2() { asm volatile("s_waitcnt vmcnt(2)" ::: "memory"); }
__device__ __forceinline__ void wait_lgkm0() { asm volatile("s_waitcnt lgkmcnt(0)" ::: "memory"); }

// ================= bf16 MFMA GEMM, 128x128 / 8 waves / 3-deep gload_lds ring =================
// R11: CONSOLIDATION. Design-space ledger (measured totals): R5 all-LDS ring-3 = 535.8;
// B-direct depth-1 = 679; B-direct depth-2 = 599; 256^2 @1/CU = 677; 128x256 @2/CU = 566;
// ring-2 @4/CU = 542. R5's config is the optimum: occupancy x LDS-traffic trade curve
// (eff(16w)/eff(24w) ~ 0.57 fitted from R5/R9) says further tile growth loses.
// This kernel is R5-exact:
//   * 128x128 tile, 512 thr (8 waves, 2M x 4N; wave 64x32, acc[4][2]).
//   * A+B via global_load_lds 16B, 3-deep ring (48KB); ONE load per plane per tile
//     (512 lanes x 16B = full 128x32 tile). Counted s_waitcnt vmcnt(2) at tile end
//     (t+1 landed, t+2's 2 loads stay in flight - never drains mid-loop).
//   * Global-side XOR swizzle (c ^ ((row>>1)&3)): frag ds_read_b128 conflict-free
//     (rule 21; SQ_LDS_BANK_CONFLICT == 0 measured in this config).
//   * s_setprio around MFMA; ONE barrier per K-tile; bijective XCD swizzle, ntc
//     fastest (A-sharers same XCD).
//   * epi1 (bf16 out): full-line epilogue via per-wave LDS shuffle (64 rows x 80B),
//     bf16x8 stores -> full 64B lines (fixes R1's half-line double-writeback).
//     epi0/2 (fp32 out): direct stores already full-line.
// epi 0: C0 fp32 (ld N) = acc + bias
// epi 1: N=1024; bn<512 -> C1b bf16 (ld 512); bn>=512 -> sigmoid -> C1 bf16 (ld 512)
// epi 2: C0 fp32 (ld N) = acc + bias + res
__global__ __launch_bounds__(512, 4) void gemm_k(
    const __bf16* __restrict__ A, const __bf16* __restrict__ Bt,
    const float* __restrict__ bias, const float* __restrict__ res,
    float* __restrict__ C0, __bf16* __restrict__ C1, __bf16* __restrict__ C1b,
    int N, int K, int epi)
{
  __shared__ __bf16 SM[3 * 4096 * 2];   // 48 KB: A ring [3][4096] then B ring [3][4096]
  __bf16 (*Asm)[4096] = (__bf16(*)[4096])SM;
  __bf16 (*Bsm)[4096] = (__bf16(*)[4096])(SM + 3 * 4096);

  const int tid  = threadIdx.x;
  const int w    = tid >> 6;
  const int lane = tid & 63;
  const int quad = lane >> 4;
  const int l16  = lane & 15;
  const int wm   = (w >> 2) << 6;       // 2 M-waves x 64 rows
  const int wn   = (w & 3) << 5;        // 4 N-waves x 32 cols

  // grid decode: bijective XCD swizzle, then ntc fastest (A-sharers adjacent per XCD)
  const int nwg = gridDim.x;
  const int cpx = nwg >> 3;
  const int lin = (blockIdx.x & 7) * cpx + (blockIdx.x >> 3);
  const int nbn = N >> 7;               // 128-wide N tiles (4 or 8)
  const int sh  = (nbn == 8) ? 3 : 2;
  const int mt  = lin >> sh;
  const int ntc = lin & (nbn - 1);
  const int bm  = mt << 7;
  const int bn  = ntc << 7;

  const __bf16* Ab = A  + (size_t)bm * K;
  const __bf16* Bb = Bt + (size_t)bn * K;
  const int nk = K >> 5;

  f32x4 acc[4][2];
  #pragma unroll
  for (int i = 0; i < 4; ++i)
    #pragma unroll
    for (int j = 0; j < 2; ++j) acc[i][j] = (f32x4){0.f, 0.f, 0.f, 0.f};

  // staging: 512 threads x 16B = one 128x32 tile per instruction. LDS lane-linear
  // (gload_lds requirement); global col-chunk pre-swizzled so swizzled frag reads see
  // linear data (rule 21): LDS[r][sl] = G[r][sl ^ ((r>>1)&3)].
  #define STG(P, gb, tile, buf) {                                               \
    const int r_ = tid >> 2, c_ = tid & 3;                                      \
    gload16(gb + (size_t)r_ * K + ((tile) << 5) + ((c_ ^ ((r_ >> 1) & 3)) << 3),\
            &P[buf][tid << 3]);                                                 \
  }

  // prologue: stage tiles 0,1 (4 loads); vmcnt(2) leaves tile1's 2 in flight
  STG(Asm, Ab, 0, 0) STG(Bsm, Bb, 0, 0)
  STG(Asm, Ab, 1, 1) STG(Bsm, Bb, 1, 1)
  wait_vm2();
  __builtin_amdgcn_s_barrier();

  int cur = 0;
  for (int t = 0; t < nk; ++t) {
    const int nx2 = (cur == 0) ? 2 : cur - 1;    // (cur+2)%3 : buffer for tile t+2
    const bool st = (t + 2 < nk);

    // issue next-next tile's loads FIRST (max latency cover; target buffer was fully
    // read in tile t-1, barrier-ordered)
    if (st) {
      STG(Asm, Ab, t + 2, nx2)
      STG(Bsm, Bb, t + 2, nx2)
    }

    bf16x8 af[4], bfr[2];
    #pragma unroll
    for (int i = 0; i < 4; ++i) {
      const int m = wm + i * 16 + l16;
      af[i] = *(const bf16x8*)(&Asm[cur][m * 32 + ((quad ^ ((m >> 1) & 3)) << 3)]);
    }
    #pragma unroll
    for (int j = 0; j < 2; ++j) {
      const int n = wn + j * 16 + l16;
      bfr[j] = *(const bf16x8*)(&Bsm[cur][n * 32 + ((quad ^ ((n >> 1) & 3)) << 3)]);
    }

    __builtin_amdgcn_s_setprio(1);
    #pragma unroll
    for (int i = 0; i < 4; ++i) {
      acc[i][0] = __builtin_amdgcn_mfma_f32_16x16x32_bf16(af[i], bfr[0], acc[i][0], 0, 0, 0);
      acc[i][1] = __builtin_amdgcn_mfma_f32_16x16x32_bf16(af[i], bfr[1], acc[i][1], 0, 0, 0);
    }
    __builtin_amdgcn_s_setprio(0);

    // tile end: counted wait (tile t+1 landed; tile t+2's 2 loads stay in flight)
    if (st) { wait_vm2(); } else { wait_vm0(); }
    __builtin_amdgcn_s_barrier();
    cur = (cur == 2) ? 0 : cur + 1;
  }
  #undef STG

  // ---- epilogue. C/D layout: col = lane&15, row = quad*4 + reg  [m89-verified] ----
  if (epi == 1) {
    // full-line bf16 path: scatter through per-wave LDS (64 rows x 80B stride), read
    // back bf16x8 -> 16B/lane stores; each 4-lane group covers a full 64B line.
    const bool dosig = (bn >= 512);
    __bf16* dst = dosig ? C1 : C1b;
    const int cb = dosig ? (bn - 512) : bn;
    char* wb = (char*)SM + w * 5120;             // 8 waves x 5120 B = 40 KB <= 48 KB
    #pragma unroll
    for (int i = 0; i < 4; ++i)
      #pragma unroll
      for (int j = 0; j < 2; ++j) {
        const float bv = bias[bn + wn + j * 16 + l16];
        #pragma unroll
        for (int r = 0; r < 4; ++r) {
          float v = acc[i][j][r] + bv;
          if (dosig) v = 1.f / (1.f + expf(-v));
          *(__bf16*)(wb + (i * 16 + quad * 4 + r) * 80 + (j * 16 + l16) * 2) = (__bf16)v;
        }
      }
    wait_lgkm0();                                 // wave-local; no barrier needed
    #pragma unroll
    for (int s = 0; s < 4; ++s) {
      const int rr = s * 16 + (lane >> 2);        // 0..63 within wave tile
      bf16x8 vv = *(bf16x8*)(wb + rr * 80 + (lane & 3) * 16);
      const int grow = bm + wm + rr;
      *(bf16x8*)(dst + (size_t)grow * 512 + cb + wn + (lane & 3) * 8) = vv;
    }
  } else {
    // fp32 path: 16 lanes x 4B = full 64B line per store group already
    #pragma unroll
    for (int j = 0; j < 2; ++j) {
      const int col = wn + j * 16 + l16;
      const float bv = bias[bn + col];
      #pragma unroll
      for (int i = 0; i < 4; ++i) {
        const int row0 = bm + wm + i * 16 + quad * 4;
        #pragma unroll
        for (int r = 0; r < 4; ++r) {
          float v = acc[i][j][r] + bv;
          size_t off = (size_t)(row0 + r) * N + bn + col;
          if (epi == 2) v += res[off];
          C0[off] = v;
        }
      }
    }
  }
}

// ================= fused preamble: tokens cvt + 3 weight transposes (R11) =================
// One dispatch replaces cvt_k + tr_k x3 (saves ~3 launch gaps; bodies identical).
// Block ranges: [0,6144) cvt; [6144,6528) in_w tr; [6528,8576) iw tr; [8576,9600) ow tr.
__global__ __launch_bounds__(256) void prep_k(
    const float* __restrict__ tokens, __bf16* __restrict__ tb16,
    const float* __restrict__ in_w, __bf16* __restrict__ inwT,
    const float* __restrict__ iw,  __bf16* __restrict__ iwT,
    const float* __restrict__ ow,  __bf16* __restrict__ owT)
{
  __shared__ float t[32][33];
  const int bx = blockIdx.x;
  if (bx < 6144) {
    // ---- cvt: fp32 -> bf16, 8 elems/thread ----
    size_t i = ((size_t)bx * 256 + threadIdx.x) * 8;
    float4 a = *(const float4*)(tokens + i);
    float4 b = *(const float4*)(tokens + i + 4);
    bf16x8 v;
    v[0] = (__bf16)a.x; v[1] = (__bf16)a.y; v[2] = (__bf16)a.z; v[3] = (__bf16)a.w;
    v[4] = (__bf16)b.x; v[5] = (__bf16)b.y; v[6] = (__bf16)b.z; v[7] = (__bf16)b.w;
    *(bf16x8*)(tb16 + i) = v;
    return;
  }
  // ---- transpose KxN fp32 -> NxK bf16 ----
  int K, N, xb, yb, zb;
  const float* s;
  __bf16* d;
  size_t sstr, dstr;
  int b2 = bx - 6144;
  if (b2 < 384) {            // in_w: 768x512, tiles 16(N) x 24(K)
    K = 768; N = 512; xb = b2 & 15; yb = b2 >> 4; zb = 0;
    s = in_w; d = inwT; sstr = 0; dstr = 0;
  } else if ((b2 -= 384) < 2048) {   // iw: 4 x 512x1024, tiles 32(N) x 16(K) x 4
    K = 512; N = 1024; xb = b2 & 31; yb = (b2 >> 5) & 15; zb = b2 >> 9;
    s = iw; d = iwT; sstr = (size_t)512 * 1024; dstr = (size_t)1024 * 512;
  } else {                   // ow: 4 x 512x512, tiles 16(N) x 16(K) x 4
    b2 -= 2048;
    K = 512; N = 512; xb = b2 & 15; yb = (b2 >> 4) & 15; zb = b2 >> 8;
    s = ow; d = owT; sstr = (size_t)512 * 512; dstr = (size_t)512 * 512;
  }
  s += zb * sstr;
  d += zb * dstr;
  const int n0 = xb * 32, k0 = yb * 32;
  const int tx = threadIdx.x & 31, ty = threadIdx.x >> 5;   // 32x8
  #pragma unroll
  for (int i = 0; i < 4; ++i)
    t[ty + i * 8][tx] = s[(size_t)(k0 + ty + i * 8) * N + n0 + tx];
  __syncthreads();
  #pragma unroll
  for (int i = 0; i < 4; ++i)
    d[(size_t)(n0 + ty + i * 8) * K + k0 + tx] = (__bf16)t[tx][ty + i * 8];
}

// ---------------- LayerNorm over D=512, one wave per position, bf16 out ----------------
__global__ __launch_bounds__(256) void ln_k(const float* __restrict__ x, const float* __restrict__ w,
                                            const float* __restrict__ bv, __bf16* __restrict__ out)
{
  int gw = (blockIdx.x * 256 + threadIdx.x) >> 6;   // position
  int lane = threadIdx.x & 63;
  const float* xp = x + ((size_t)gw << 9) + lane * 8;
  float4 u0 = *(const float4*)xp;
  float4 u1 = *(const float4*)(xp + 4);
  float v[8] = {u0.x,u0.y,u0.z,u0.w,u1.x,u1.y,u1.z,u1.w};
  float s = 0.f;
  #pragma unroll
  for (int j = 0; j < 8; ++j) s += v[j];
  #pragma unroll
  for (int off = 32; off; off >>= 1) s += __shfl_xor(s, off, 64);
  float mu = s * (1.f/512.f);
  float q = 0.f;
  #pragma unroll
  for (int j = 0; j < 8; ++j) { float d = v[j] - mu; q += d*d; }
  #pragma unroll
  for (int off = 32; off; off >>= 1) q += __shfl_xor(q, off, 64);
  float rstd = rsqrtf(q * (1.f/512.f) + 1e-5f);
  int dch = lane * 8;
  float4 w0 = *(const float4*)(w + dch),  w1 = *(const float4*)(w + dch + 4);
  float4 b0 = *(const float4*)(bv + dch), b1 = *(const float4*)(bv + dch + 4);
  float wv[8] = {w0.x,w0.y,w0.z,w0.w,w1.x,w1.y,w1.z,w1.w};
  float bb[8] = {b0.x,b0.y,b0.z,b0.w,b1.x,b1.y,b1.z,b1.w};
  bf16x8 ov;
  #pragma unroll
  for (int j = 0; j < 8; ++j) ov[j] = (__bf16)((v[j] - mu) * rstd * wv[j] + bb[j]);
  *(bf16x8*)(out + ((size_t)gw << 9) + dch) = ov;
}

// ================= Fully-fused conv + 2D scan, 16 ch/block, 2 blocks/CU (R4-proven) =================
__device__ __forceinline__ float sig_a(float al) {
  float a = 1.f / (1.f + expf(-al));
  return fminf(fmaxf(a, 1e-4f), 1.f - 1e-4f);
}

#define CST 544   // chunk stride in elements: 32*16 + 32 pad (1088 B)

__global__ __launch_bounds__(512, 4) void scan2d_k(
    const __bf16* __restrict__ xin, const float* __restrict__ cw, const float* __restrict__ cb,
    const float* __restrict__ alog, const float* __restrict__ bvec, const float* __restrict__ cvec,
    const float* __restrict__ dvec, const __bf16* __restrict__ gate, __bf16* __restrict__ yo)
{
  __shared__ __bf16 T[32 * CST];    // xin tile; partial park in phase C. 34 KB
  __shared__ __bf16 Y[32 * CST];    // u tile. 34 KB
  __shared__ float  S[4][32][16];   // chunk sums: rowF,rowB,colF,colB. 8 KB
  const int tid = threadIdx.x;
  const int bx  = blockIdx.x;
  const int cg  = ((bx & 7) << 2) | (bx >> 3);   // channel group of 16; line-mates same XCD
  const int b   = blockIdx.y;
  const int ch  = tid & 15;
  const int c0  = tid >> 4;         // 0..31; thread owns chunk c0
  const int d   = (cg << 4) + ch;

  const float a   = sig_a(alog[d]);
  const float lna = logf(a);
  const float ia  = 1.f / a;
  const float bb  = bvec[d];
  const float sc  = 0.25f * cvec[d];
  const float dd  = dvec[d];

  const __bf16* ub = xin + ((size_t)b << 19) + (cg << 4);

  // ---- load xin tile: 4 x bf16x8 per thread, 16 B/lane ----
  #pragma unroll
  for (int i = 0; i < 4; ++i) {
    int f = tid + i * 512;          // 16B chunk id, 0..2047
    int pos = f >> 1, half = f & 1;
    *(bf16x8*)(T + (pos >> 5) * CST + ((pos & 31) << 4) + (half << 3))
        = *(const bf16x8*)(ub + (size_t)pos * 512 + (half << 3));
  }
  // conv weights while loads are in flight
  float w00 = cw[(0 << 9) + d], w01 = cw[(1 << 9) + d], w02 = cw[(2 << 9) + d];
  float w10 = cw[(3 << 9) + d], w11 = cw[(4 << 9) + d], w12 = cw[(5 << 9) + d];
  float w20 = cw[(6 << 9) + d], w21 = cw[(7 << 9) + d], w22 = cw[(8 << 9) + d];
  const float cbv = cb[d];
  // scan bases (loop-invariant; direct expf avoids 0*inf at extreme a)
  const float A0f = expf((float)(c0 << 5) * lna),        R0f = expf((float)(c0 << 5) * -lna);
  const float A0b = expf((float)((31 - c0) << 5) * lna), R0b = expf((float)((31 - c0) << 5) * -lna);
  __syncthreads();

  // ---- phase 0: depthwise 3x3 conv + SiLU, row c0 -> Y ----
  {
    const bool up = (c0 > 0);
    const bool dn = (c0 < 31);
    float a0 = 0.f, a1 = 0.f, a2 = 0.f;                                  // col -1
    float b0 = up ? (float)T[(c0 - 1) * CST + ch] : 0.f;                 // col 0
    float b1 =      (float)T[c0 * CST + ch];
    float b2 = dn ? (float)T[(c0 + 1) * CST + ch] : 0.f;
    #pragma unroll 4
    for (int ww = 0; ww < 32; ++ww) {
      float e0 = 0.f, e1 = 0.f, e2 = 0.f;                                // col ww+1
      if (ww < 31) {
        e0 = up ? (float)T[(c0 - 1) * CST + ((ww + 1) << 4) + ch] : 0.f;
        e1 =      (float)T[c0 * CST + ((ww + 1) << 4) + ch];
        e2 = dn ? (float)T[(c0 + 1) * CST + ((ww + 1) << 4) + ch] : 0.f;
      }
      float acc0 = cbv;
      acc0 = fmaf(a0, w00, acc0); acc0 = fmaf(b0, w01, acc0); acc0 = fmaf(e0, w02, acc0);
      acc0 = fmaf(a1, w10, acc0); acc0 = fmaf(b1, w11, acc0); acc0 = fmaf(e1, w12, acc0);
      acc0 = fmaf(a2, w20, acc0); acc0 = fmaf(b2, w21, acc0); acc0 = fmaf(e2, w22, acc0);
      acc0 = acc0 / (1.f + expf(-acc0));
      Y[c0 * CST + (ww << 4) + ch] = (__bf16)acc0;
      a0 = b0; a1 = b1; a2 = b2; b0 = e0; b1 = e1; b2 = e2;
    }
  }
  __syncthreads();

  // one scan step: r += u*bb/max(apr,1e-20) with tracked reciprocal
  #define STEP(r_, uu_, apr_, rp_)                                 \
    { float rr_ = (apr_ < 1e-20f) ? 1e20f : rp_;                   \
      r_ = fmaf((uu_) * bb, rr_, r_); }

  // ---- phase A: 4 chunk sums (rowF/rowB/colF/colB) in one loop ----
  {
    float pf = A0f, qf = R0f, pb = A0b, qb = R0b;
    float s0 = 0.f, s1 = 0.f, s2 = 0.f, s3 = 0.f;
    #pragma unroll 4
    for (int j = 0; j < 32; ++j) {
      float urf = (float)Y[c0 * CST + (j << 4) + ch];
      float urb = (float)Y[c0 * CST + ((31 - j) << 4) + ch];
      float ucf = (float)Y[j * CST + (c0 << 4) + ch];
      float ucb = (float)Y[(31 - j) * CST + (c0 << 4) + ch];
      STEP(s0, urf, pf, qf)  STEP(s2, ucf, pf, qf)
      STEP(s1, urb, pb, qb)  STEP(s3, ucb, pb, qb)
      pf *= a; qf *= ia; pb *= a; qb *= ia;
    }
    S[0][c0][ch] = s0; S[1][c0][ch] = s1; S[2][c0][ch] = s2; S[3][c0][ch] = s3;
  }
  __syncthreads();

  // ---- phase B: exclusive prefix (F arrays) / exclusive suffix (B arrays) ----
  if (tid < 64) {
    int arr = tid >> 4, ch2 = tid & 15;
    float run = 0.f;
    if ((arr & 1) == 0) {
      #pragma unroll 4
      for (int cc = 0; cc < 32; ++cc) { float v = S[arr][cc][ch2]; S[arr][cc][ch2] = run; run += v; }
    } else {
      #pragma unroll 4
      for (int cc = 31; cc >= 0; --cc) { float v = S[arr][cc][ch2]; S[arr][cc][ch2] = run; run += v; }
    }
  }
  __syncthreads();

  // ---- C-col fwd: raw partial -> T  (column c0: pos = j*32+c0 -> chunk j, in-chunk c0) ----
  {
    float r = S[2][c0][ch];
    float p = A0f, q = R0f;
    #pragma unroll 4
    for (int j = 0; j < 32; ++j) {
      int i0 = j * CST + (c0 << 4) + ch;
      float u = (float)Y[i0];
      float ap = fmaxf(p, 1e-20f);
      STEP(r, u, p, q)
      T[i0] = (__bf16)(r * ap);
      p *= a; q *= ia;
    }
  }
  // ---- C-col bwd: T = sc*(T + r*ap)  [same-thread RMW] ----
  {
    float r = S[3][c0][ch];
    float p = A0b, q = R0b;
    #pragma unroll 4
    for (int j = 31; j >= 0; --j) {
      int i0 = j * CST + (c0 << 4) + ch;
      float u = (float)Y[i0];
      float ap = fmaxf(p, 1e-20f);
      STEP(r, u, p, q)
      T[i0] = (__bf16)(sc * ((float)T[i0] + r * ap));
      p *= a; q *= ia;
    }
  }
  __syncthreads();   // row threads read other threads' col finals

  // ---- C-row fwd: T += sc*(r*ap)  (row c0: chunk c0, in-chunk j) ----
  {
    float r = S[0][c0][ch];
    float p = A0f, q = R0f;
    #pragma unroll 4
    for (int j = 0; j < 32; ++j) {
      int i0 = c0 * CST + (j << 4) + ch;
      float u = (float)Y[i0];
      float ap = fmaxf(p, 1e-20f);
      STEP(r, u, p, q)
      T[i0] = (__bf16)((float)T[i0] + sc * (r * ap));
      p *= a; q *= ia;
    }
  }
  // ---- C-row bwd: finalize + d*u, *gate, write out ----
  {
    const __bf16* gb = gate + ((size_t)b << 19) + (cg << 4) + ch;
    __bf16* yb = yo + ((size_t)b << 19) + (cg << 4) + ch;
    float r = S[1][c0][ch];
    float p = A0b, q = R0b;
    #pragma unroll 4
    for (int j = 31; j >= 0; --j) {
      int pp = (c0 << 5) + j;
      int i0 = c0 * CST + (j << 4) + ch;
      float u = (float)Y[i0];
      float ap = fmaxf(p, 1e-20f);
      STEP(r, u, p, q)
      float y0 = (float)T[i0] + sc * (r * ap) + dd * u;
      yb[(size_t)pp * 512] = (__bf16)(y0 * (float)gb[(size_t)pp * 512]);
      p *= a; q *= ia;
    }
  }
  #undef STEP
}

// ---------------- mean over 1024 positions (bf16 in) -> (16, 512) fp32 ----------------
__global__ __launch_bounds__(256) void reduce_k(const __bf16* __restrict__ hn, float* __restrict__ out)
{
  __shared__ float part[4][64];
  int l = threadIdx.x & 63;       // channel within group
  int q = threadIdx.x >> 6;       // position quarter
  int d = blockIdx.y * 64 + l;
  int b = blockIdx.x;
  const __bf16* p = hn + ((size_t)b << 19) + d + ((size_t)(q * 256) << 9);
  float s0 = 0.f, s1 = 0.f, s2 = 0.f, s3 = 0.f;
  for (int t = 0; t < 256; t += 4) {
    s0 += (float)p[(size_t)(t+0) << 9];
    s1 += (float)p[(size_t)(t+1) << 9];
    s2 += (float)p[(size_t)(t+2) << 9];
    s3 += (float)p[(size_t)(t+3) << 9];
  }
  part[q][l] = (s0 + s1) + (s2 + s3);
  __syncthreads();
  if (threadIdx.x < 64)
    out[b * 512 + d] = (part[0][l] + part[1][l] + part[2][l] + part[3][l]) * (1.f / 1024.f);
}

extern "C" void kernel_launch(void* const* d_in, const int* in_sizes, int n_in,
                              void* d_out, int out_size, void* d_ws, size_t ws_size,
                              hipStream_t stream)
{
  const float* tokens = (const float*)d_in[0];
  const float* in_w   = (const float*)d_in[1];
  const float* in_b   = (const float*)d_in[2];
  const float* nw     = (const float*)d_in[3];
  const float* nb     = (const float*)d_in[4];
  const float* iw     = (const float*)d_in[5];
  const float* ib     = (const float*)d_in[6];
  const float* cw     = (const float*)d_in[7];
  const float* cb     = (const float*)d_in[8];
  const float* al     = (const float*)d_in[9];
  const float* bbv    = (const float*)d_in[10];
  const float* ccv    = (const float*)d_in[11];
  const float* ddv    = (const float*)d_in[12];
  const float* ow     = (const float*)d_in[13];
  const float* obv    = (const float*)d_in[14];
  const float* onw    = (const float*)d_in[15];
  const float* onb    = (const float*)d_in[16];

  // workspace layout (~115 MB):
  float*  x     = (float*)d_ws;                      // fp32 residual (33.5 MB)
  __bf16* hy16  = (__bf16*)(x + PP);                 // bf16 h / yg / final-ln (16.8 MB)
  __bf16* xin16 = hy16 + PP;                         // bf16 x_in (16.8 MB)
  __bf16* g16   = xin16 + PP;                        // bf16 gate (16.8 MB)
  __bf16* iwT   = g16 + PP;                          // 4x(1024x512) bf16 (4.2 MB)
  __bf16* owT   = iwT + (size_t)4 * 1024 * 512;      // 4x(512x512) bf16 (2.1 MB)
  __bf16* tb16  = owT + (size_t)4 * 512 * 512;       // tokens bf16 (25.2 MB)
  __bf16* inwT  = xin16;                             // in_proj_w^T bf16 (pre-loop alias)

  // --- fused weight/input conversion (one dispatch; ranges: 6144 cvt + 384 + 2048 + 1024 tr) ---
  prep_k<<<9600, 256, 0, stream>>>(tokens, tb16, in_w, inwT, iw, iwT, ow, owT);

  // x = tokens @ in_proj_w + b   (128 M-tiles x 4 N-tiles = 512 blocks, 2/CU)
  gemm_k<<<512, 512, 0, stream>>>(tb16, inwT, in_b, nullptr, x, nullptr, nullptr,
                                  512, 768, 0);

  for (int i = 0; i < 4; ++i) {
    ln_k<<<4096, 256, 0, stream>>>(x, nw + i*512, nb + i*512, hy16);
    // (h @ iw + ib): 128 x 8 = 1024 blocks (R5-proven best)
    gemm_k<<<1024, 512, 0, stream>>>(hy16, iwT + (size_t)i*1024*512, ib + i*1024,
                                     nullptr, nullptr, g16, xin16, 1024, 512, 1);
    // 32 ch-groups x 16 batch = 512 blocks, 2/CU
    scan2d_k<<<dim3(32, 16), 512, 0, stream>>>(xin16, cw + i*9*512, cb + i*512,
                                               al + i*512, bbv + i*512, ccv + i*512,
                                               ddv + i*512, g16, hy16);
    // (yg @ ow + ob + x): 128 x 4 = 512 blocks
    gemm_k<<<512, 512, 0, stream>>>(hy16, owT + (size_t)i*512*512, obv + i*512,
                                    x, x, nullptr, nullptr, 512, 512, 2);
  }

  ln_k<<<4096, 256, 0, stream>>>(x, onw, onb, hy16);
  reduce_k<<<dim3(16, 8), 256, 0, stream>>>(hy16, (float*)d_out);
}